// Round 5
// baseline (947.621 us; speedup 1.0000x reference)
//
#include <hip/hip_runtime.h>
#include <hip/hip_bf16.h>
#include <math.h>

#define NN     10000
#define EE     320000
#define IN_CH  739
#define CC     64
#define GG     64
#define NLAYER 9
#define KTILES 12   // ceil(739/64)

__device__ __forceinline__ float eluf(float x) { return x > 0.f ? x : expm1f(x); }
__device__ __forceinline__ float softplusf(float x) {
    return fmaxf(x, 0.f) + log1pf(expf(-fabsf(x)));
}
__device__ __forceinline__ float wave_sum(float v) {
#pragma unroll
    for (int off = 32; off > 0; off >>= 1) v += __shfl_xor(v, off, 64);
    return v;
}

// ---------------------------------------------------------------------------
// InitFeat + UpdateZ(k=0) as a register-tiled GEMM.
// Block: 256 thr, 64 rows x 64 cols of h. Thread: 4 rows x 4 cols.
// ---------------------------------------------------------------------------
__global__ __launch_bounds__(256) void k_init(
    const float* __restrict__ x,
    const float* __restrict__ w0, const float* __restrict__ b0,
    const float* __restrict__ w1, const float* __restrict__ b1,
    const float* __restrict__ hop_att0, const float* __restrict__ hop_bias0,
    float* __restrict__ xout, float* __restrict__ zout)
{
    __shared__ float xs[64 * 68];   // [row][k], stride 68
    __shared__ float ws[64 * 64];   // [k][col], stride 64
    const int tid = threadIdx.x;
    const int cg = tid & 15;        // col group: cols cg*4 .. cg*4+3
    const int rg = tid >> 4;        // row group: rows rg*4 .. rg*4+3
    const int R0 = blockIdx.x * 64; // 157 blocks, last partial

    const int sk = tid & 63;        // staging: k-in-tile (x) / col (w)
    const int sr = tid >> 6;        // staging: row base (steps of 4)

    float xr[16], wr[16];
    float acc[4][4];
    const float4 b0v = *(const float4*)&b0[cg * 4];
#pragma unroll
    for (int j = 0; j < 4; ++j) {
        acc[j][0] = b0v.x; acc[j][1] = b0v.y;
        acc[j][2] = b0v.z; acc[j][3] = b0v.w;
    }

    // prefetch tile 0
#pragma unroll
    for (int i = 0; i < 16; ++i) {
        const int r = sr + 4 * i;
        const int gr = R0 + r;
        xr[i] = (gr < NN && sk < IN_CH) ? x[(size_t)gr * IN_CH + sk] : 0.f;
        wr[i] = (r < IN_CH) ? w0[r * CC + sk] : 0.f;
    }

    for (int t = 0; t < KTILES; ++t) {
        __syncthreads();
#pragma unroll
        for (int i = 0; i < 16; ++i) {
            const int r = sr + 4 * i;
            xs[r * 68 + sk] = xr[i];
            ws[r * 64 + sk] = wr[i];
        }
        __syncthreads();
        if (t + 1 < KTILES) {
            const int k0 = (t + 1) * 64;
#pragma unroll
            for (int i = 0; i < 16; ++i) {
                const int r = sr + 4 * i;
                const int gr = R0 + r;
                const int gk = k0 + sk;
                xr[i] = (gr < NN && gk < IN_CH) ? x[(size_t)gr * IN_CH + gk] : 0.f;
                const int wk = k0 + r;
                wr[i] = (wk < IN_CH) ? w0[wk * CC + sk] : 0.f;
            }
        }
#pragma unroll 4
        for (int k4 = 0; k4 < 64; k4 += 4) {
            float4 xv[4], wv[4];
#pragma unroll
            for (int j = 0; j < 4; ++j)
                xv[j] = *(const float4*)&xs[(rg * 4 + j) * 68 + k4];
#pragma unroll
            for (int q = 0; q < 4; ++q)
                wv[q] = *(const float4*)&ws[(k4 + q) * 64 + cg * 4];
#pragma unroll
            for (int j = 0; j < 4; ++j) {
                const float* xf = (const float*)&xv[j];
#pragma unroll
                for (int q = 0; q < 4; ++q) {
                    const float* wf = (const float*)&wv[q];
#pragma unroll
                    for (int i = 0; i < 4; ++i)
                        acc[j][i] = fmaf(xf[q], wf[i], acc[j][i]);
                }
            }
        }
    }

    // ---- GEMM2: elu(h) @ w1 + b1 (single 64-k tile, LDS reuse) ----
    __syncthreads();
#pragma unroll
    for (int j = 0; j < 4; ++j) {
        float4 hv;
        hv.x = eluf(acc[j][0]); hv.y = eluf(acc[j][1]);
        hv.z = eluf(acc[j][2]); hv.w = eluf(acc[j][3]);
        *(float4*)&xs[(rg * 4 + j) * 68 + cg * 4] = hv;
    }
#pragma unroll
    for (int i = 0; i < 16; ++i) {
        const int r = sr + 4 * i;
        ws[r * 64 + sk] = w1[r * CC + sk];
    }
    __syncthreads();

    float acc2[4][4];
    const float4 b1v = *(const float4*)&b1[cg * 4];
#pragma unroll
    for (int j = 0; j < 4; ++j) {
        acc2[j][0] = b1v.x; acc2[j][1] = b1v.y;
        acc2[j][2] = b1v.z; acc2[j][3] = b1v.w;
    }
#pragma unroll 4
    for (int k4 = 0; k4 < 64; k4 += 4) {
        float4 xv[4], wv[4];
#pragma unroll
        for (int j = 0; j < 4; ++j)
            xv[j] = *(const float4*)&xs[(rg * 4 + j) * 68 + k4];
#pragma unroll
        for (int q = 0; q < 4; ++q)
            wv[q] = *(const float4*)&ws[(k4 + q) * 64 + cg * 4];
#pragma unroll
        for (int j = 0; j < 4; ++j) {
            const float* xf = (const float*)&xv[j];
#pragma unroll
            for (int q = 0; q < 4; ++q) {
                const float* wf = (const float*)&wv[q];
#pragma unroll
                for (int i = 0; i < 4; ++i)
                    acc2[j][i] = fmaf(xf[q], wf[i], acc2[j][i]);
            }
        }
    }

    // ---- epilogue: write h2 to LDS, then wave-per-row hop attention ----
    __syncthreads();   // done reading ws (w1)
#pragma unroll
    for (int j = 0; j < 4; ++j)
        *(float4*)&ws[(rg * 4 + j) * 64 + cg * 4] =
            make_float4(acc2[j][0], acc2[j][1], acc2[j][2], acc2[j][3]);
    __syncthreads();

    const int c = tid & 63;
    const int wv4 = tid >> 6;
    const float ha = hop_att0[c];
    const float hb = hop_bias0[0];
#pragma unroll
    for (int rr = 0; rr < 16; ++rr) {
        const int r = wv4 + 4 * rr;
        const float v = ws[r * 64 + c];
        const float attn = wave_sum(ha * eluf(v)) + hb;
        const int row = R0 + r;
        if (row < NN) {
            xout[row * CC + c] = v;
            zout[row * CC + c] = v * attn;
        }
    }
}

// ---------------------------------------------------------------------------
// CSR build (dst-sorted): histogram -> exclusive scan -> scatter
// ---------------------------------------------------------------------------
__global__ __launch_bounds__(256) void k_hist(const int* __restrict__ ei,
                                              int* __restrict__ deg)
{
    const int e = blockIdx.x * 256 + threadIdx.x;   // grid == EE/256
    atomicAdd(&deg[ei[EE + e]], 1);
}

__global__ __launch_bounds__(256) void k_scan(const int* __restrict__ deg,
                                              int* __restrict__ offs)
{
    __shared__ int part[256];
    const int tid = threadIdx.x;
    const int start = tid * 40;
    const int end = start + 40 < NN ? start + 40 : NN;
    int sum = 0;
    for (int i = start; i < end; ++i) sum += deg[i];
    part[tid] = sum;
    __syncthreads();
    if (tid == 0) {
        int run = 0;
        for (int i = 0; i < 256; ++i) { int t = part[i]; part[i] = run; run += t; }
    }
    __syncthreads();
    int run = part[tid];
    for (int i = start; i < end; ++i) { offs[i] = run; run += deg[i]; }
}

__global__ __launch_bounds__(256) void k_scatter(
    const int* __restrict__ ei, const int* __restrict__ offs,
    int* __restrict__ cursor, int* __restrict__ csr_src,
    int* __restrict__ csr_dst)
{
    const int e = blockIdx.x * 256 + threadIdx.x;
    const int d = ei[EE + e];
    const int pos = offs[d] + atomicAdd(&cursor[d], 1);
    csr_src[pos] = ei[e];
    csr_dst[pos] = d;
}

// ---------------------------------------------------------------------------
// Group boundaries from sorted batch: gstart[g] = first node with batch>=g.
// ---------------------------------------------------------------------------
__global__ __launch_bounds__(256) void k_bounds(const int* __restrict__ batch,
                                                int* __restrict__ gstart)
{
    const int n = blockIdx.x * 256 + threadIdx.x;   // grid covers NN
    if (n >= NN) return;
    if (n == 0)
        for (int g = 0; g <= batch[0]; ++g) gstart[g] = 0;
    else {
        const int b0 = batch[n - 1], b1 = batch[n];
        for (int g = b0 + 1; g <= b1; ++g) gstart[g] = n;
    }
    if (n == NN - 1)
        for (int g = batch[NN - 1] + 1; g <= GG; ++g) gstart[g] = NN;
}

// ---------------------------------------------------------------------------
// Edge attention in CSR order: 16 lanes per edge (4 edges/wave).
// csr_src/csr_dst reads coalesced; a_csr write sequential; adj via atomic.
// ---------------------------------------------------------------------------
__global__ __launch_bounds__(256) void k_edge_att(
    const int* __restrict__ csr_src, const int* __restrict__ csr_dst,
    const float* __restrict__ z, const float* __restrict__ conv_att,
    float scale, float* __restrict__ a_csr, float* __restrict__ adj)
{
    __shared__ float sca[CC];
    if (threadIdx.x < CC) sca[threadIdx.x] = conv_att[threadIdx.x];
    __syncthreads();

    const int e = blockIdx.x * 16 + (threadIdx.x >> 4);   // grid == EE/16
    const int l = threadIdx.x & 15;
    const int s = csr_src[e];
    const int d = csr_dst[e];
    const float4 zs = *(const float4*)(z + s * CC + l * 4);
    const float4 zd = *(const float4*)(z + d * CC + l * 4);
    float p = sca[4 * l + 0] * eluf((zs.x + zd.x) * scale);
    p = fmaf(sca[4 * l + 1], eluf((zs.y + zd.y) * scale), p);
    p = fmaf(sca[4 * l + 2], eluf((zs.z + zd.z) * scale), p);
    p = fmaf(sca[4 * l + 3], eluf((zs.w + zd.w) * scale), p);
#pragma unroll
    for (int off = 8; off > 0; off >>= 1) p += __shfl_xor(p, off, 64);
    if (l == 0) {
        const float ae = softplusf(p) + 1e-6f;
        a_csr[e] = ae;
        atomicAdd(&adj[d], ae);
    }
}

// ---------------------------------------------------------------------------
// Fused message gather + UpdateZ. One wave per dst node, lane = channel.
// ---------------------------------------------------------------------------
__global__ __launch_bounds__(256) void k_msg_fused(
    const int* __restrict__ offs, const int* __restrict__ deg,
    const int* __restrict__ csr_src, const float* __restrict__ a_csr,
    const float* __restrict__ adj, const float* __restrict__ x,
    float* __restrict__ xn, float* __restrict__ z,
    const float* __restrict__ hop_att, const float* __restrict__ hop_bias,
    float scale)
{
    const int n = __builtin_amdgcn_readfirstlane(
        blockIdx.x * 4 + (threadIdx.x >> 6));            // grid == NN/4
    const int c = threadIdx.x & 63;
    const int start = offs[n];
    const int len = deg[n];
    const float invd = rsqrtf(fmaxf(adj[n], 1e-32f));

    float acc = 0.f;
    for (int base = 0; base < len; base += 64) {
        const int cnt = (len - base) < 64 ? (len - base) : 64;
        int s_l = 0; float na_l = 0.f;
        if (c < cnt) {
            s_l = csr_src[start + base + c];
            na_l = a_csr[start + base + c] *
                   rsqrtf(fmaxf(adj[s_l], 1e-32f)) * invd;
        }
        int j = 0;
        for (; j + 4 <= cnt; j += 4) {
            const int s0 = __builtin_amdgcn_readlane(s_l, j);
            const int s1 = __builtin_amdgcn_readlane(s_l, j + 1);
            const int s2 = __builtin_amdgcn_readlane(s_l, j + 2);
            const int s3 = __builtin_amdgcn_readlane(s_l, j + 3);
            const float n0 = __int_as_float(__builtin_amdgcn_readlane(__float_as_int(na_l), j));
            const float n1 = __int_as_float(__builtin_amdgcn_readlane(__float_as_int(na_l), j + 1));
            const float n2 = __int_as_float(__builtin_amdgcn_readlane(__float_as_int(na_l), j + 2));
            const float n3 = __int_as_float(__builtin_amdgcn_readlane(__float_as_int(na_l), j + 3));
            const float v0 = x[s0 * CC + c];
            const float v1 = x[s1 * CC + c];
            const float v2 = x[s2 * CC + c];
            const float v3 = x[s3 * CC + c];
            acc = fmaf(v0, n0, acc);
            acc = fmaf(v1, n1, acc);
            acc = fmaf(v2, n2, acc);
            acc = fmaf(v3, n3, acc);
        }
        for (; j < cnt; ++j) {
            const int s = __builtin_amdgcn_readlane(s_l, j);
            const float na = __int_as_float(__builtin_amdgcn_readlane(__float_as_int(na_l), j));
            acc = fmaf(x[s * CC + c], na, acc);
        }
    }

    // UpdateZ (k >= 1)
    const float zv = z[n * CC + c];
    float g = hop_att[c] * eluf(acc) + hop_att[CC + c] * eluf(zv * scale);
    const float attn = wave_sum(g) + hop_bias[0];
    z[n * CC + c] = zv + acc * attn;
    xn[n * CC + c] = acc;
}

// ---------------------------------------------------------------------------
// Fused readout: block per graph (batch is sorted -> contiguous ranges).
// pooled mean + linear head, no atomics.
// ---------------------------------------------------------------------------
__global__ __launch_bounds__(256) void k_pool_head(
    const float* __restrict__ z, const int* __restrict__ gstart,
    const float* __restrict__ w_head, const float* __restrict__ b_head,
    float* __restrict__ out)
{
    __shared__ float red[4][CC];
    const int g = blockIdx.x;            // GG blocks
    const int w = threadIdx.x >> 6;
    const int c = threadIdx.x & 63;
    const int s0 = gstart[g], s1 = gstart[g + 1];

    float acc = 0.f;
    for (int n = s0 + w; n < s1; n += 4) acc += eluf(z[n * CC + c]);
    red[w][c] = acc;
    __syncthreads();
    if (w == 0) {
        const float v = red[0][c] + red[1][c] + red[2][c] + red[3][c];
        const float tot = wave_sum(v * w_head[c]);
        if (c == 0)
            out[g] = tot / fmaxf((float)(s1 - s0), 1.f) + b_head[0];
    }
}

extern "C" void kernel_launch(void* const* d_in, const int* in_sizes, int n_in,
                              void* d_out, int out_size, void* d_ws, size_t ws_size,
                              hipStream_t stream) {
    const float* x        = (const float*)d_in[0];
    const int*   ei       = (const int*)d_in[1];
    const int*   batch    = (const int*)d_in[2];
    const float* w0       = (const float*)d_in[3];
    const float* b0       = (const float*)d_in[4];
    const float* w1       = (const float*)d_in[5];
    const float* b1       = (const float*)d_in[6];
    const float* conv_att = (const float*)d_in[7];
    const float* hop_att0 = (const float*)d_in[8];
    const float* hop_bias0= (const float*)d_in[9];
    const float* hop_att  = (const float*)d_in[10];
    const float* hop_bias = (const float*)d_in[11];
    const float* w_head   = (const float*)d_in[12];
    const float* b_head   = (const float*)d_in[13];
    float* out = (float*)d_out;

    // ---- workspace layout ----
    float* xA    = (float*)d_ws;                 // NN*CC
    float* xB    = xA + NN * CC;                 // NN*CC
    float* zbuf  = xB + NN * CC;                 // NN*CC
    float* a_csr = zbuf + NN * CC;               // EE
    // zero block starts here:
    float* adj9  = a_csr + EE;                   // NLAYER*NN
    int*   deg   = (int*)(adj9 + NLAYER * NN);   // NN
    int*   cursor= deg + NN;                     // NN
    // end zero block
    int*   offs  = cursor + NN;                  // NN
    int*   csr_src = offs + NN;                  // EE
    int*   csr_dst = csr_src + EE;               // EE
    int*   gstart  = csr_dst + EE;               // GG+1

    const size_t zero_bytes = (size_t)(NLAYER * NN + NN + NN) * 4;
    hipMemsetAsync(adj9, 0, zero_bytes, stream);

    k_init<<<(NN + 63) / 64, 256, 0, stream>>>(x, w0, b0, w1, b1,
                                               hop_att0, hop_bias0, xA, zbuf);
    k_hist<<<EE / 256, 256, 0, stream>>>(ei, deg);
    k_scan<<<1, 256, 0, stream>>>(deg, offs);
    k_scatter<<<EE / 256, 256, 0, stream>>>(ei, offs, cursor, csr_src, csr_dst);
    k_bounds<<<(NN + 255) / 256, 256, 0, stream>>>(batch, gstart);

    float* xcur = xA;
    float* xnext = xB;
    for (int i = 0; i < NLAYER; ++i) {
        const int k = i + 1;
        const float scale = (float)log(1.0 / (double)k + 1.0 + 1e-6);
        float* adj = adj9 + i * NN;
        k_edge_att<<<EE / 16, 256, 0, stream>>>(csr_src, csr_dst, zbuf,
                                                conv_att + i * CC, scale,
                                                a_csr, adj);
        k_msg_fused<<<NN / 4, 256, 0, stream>>>(offs, deg, csr_src, a_csr, adj,
                                                xcur, xnext, zbuf,
                                                hop_att + i * 2 * CC,
                                                hop_bias + i, scale);
        float* t = xcur; xcur = xnext; xnext = t;
    }

    k_pool_head<<<GG, 256, 0, stream>>>(zbuf, gstart, w_head, b_head, out);
}

// Round 6
// 548.398 us; speedup vs baseline: 1.7280x; 1.7280x over previous
//
#include <hip/hip_runtime.h>
#include <hip/hip_bf16.h>
#include <math.h>

#define NN     10000
#define EE     320000
#define IN_CH  739
#define CC     64
#define GG     64
#define NLAYER 9
#define KTILES 12   // ceil(739/64)

// fast elu / softplus: |abs err| ~1e-7 vs libm, threshold is 4.5e-4
__device__ __forceinline__ float eluf(float x) {
    return x > 0.f ? x : __expf(x) - 1.f;
}
__device__ __forceinline__ float softplusf(float x) {
    return fmaxf(x, 0.f) + __logf(1.f + __expf(-fabsf(x)));
}
__device__ __forceinline__ float wave_sum(float v) {
#pragma unroll
    for (int off = 32; off > 0; off >>= 1) v += __shfl_xor(v, off, 64);
    return v;
}

// ---------------------------------------------------------------------------
// InitFeat + UpdateZ(k=0) as a register-tiled GEMM.
// Block: 256 thr, 64 rows x 64 cols of h. Thread: 4 rows x 4 cols.
// ---------------------------------------------------------------------------
__global__ __launch_bounds__(256) void k_init(
    const float* __restrict__ x,
    const float* __restrict__ w0, const float* __restrict__ b0,
    const float* __restrict__ w1, const float* __restrict__ b1,
    const float* __restrict__ hop_att0, const float* __restrict__ hop_bias0,
    float* __restrict__ xout, float* __restrict__ zout)
{
    __shared__ float xs[64 * 68];   // [row][k], stride 68
    __shared__ float ws[64 * 64];   // [k][col], stride 64
    const int tid = threadIdx.x;
    const int cg = tid & 15;        // col group: cols cg*4 .. cg*4+3
    const int rg = tid >> 4;        // row group: rows rg*4 .. rg*4+3
    const int R0 = blockIdx.x * 64; // 157 blocks, last partial

    const int sk = tid & 63;        // staging: k-in-tile (x) / col (w)
    const int sr = tid >> 6;        // staging: row base (steps of 4)

    float xr[16], wr[16];
    float acc[4][4];
    const float4 b0v = *(const float4*)&b0[cg * 4];
#pragma unroll
    for (int j = 0; j < 4; ++j) {
        acc[j][0] = b0v.x; acc[j][1] = b0v.y;
        acc[j][2] = b0v.z; acc[j][3] = b0v.w;
    }

    // prefetch tile 0
#pragma unroll
    for (int i = 0; i < 16; ++i) {
        const int r = sr + 4 * i;
        const int gr = R0 + r;
        xr[i] = (gr < NN && sk < IN_CH) ? x[(size_t)gr * IN_CH + sk] : 0.f;
        wr[i] = (r < IN_CH) ? w0[r * CC + sk] : 0.f;
    }

    for (int t = 0; t < KTILES; ++t) {
        __syncthreads();
#pragma unroll
        for (int i = 0; i < 16; ++i) {
            const int r = sr + 4 * i;
            xs[r * 68 + sk] = xr[i];
            ws[r * 64 + sk] = wr[i];
        }
        __syncthreads();
        if (t + 1 < KTILES) {
            const int k0 = (t + 1) * 64;
#pragma unroll
            for (int i = 0; i < 16; ++i) {
                const int r = sr + 4 * i;
                const int gr = R0 + r;
                const int gk = k0 + sk;
                xr[i] = (gr < NN && gk < IN_CH) ? x[(size_t)gr * IN_CH + gk] : 0.f;
                const int wk = k0 + r;
                wr[i] = (wk < IN_CH) ? w0[wk * CC + sk] : 0.f;
            }
        }
#pragma unroll 4
        for (int k4 = 0; k4 < 64; k4 += 4) {
            float4 xv[4], wv[4];
#pragma unroll
            for (int j = 0; j < 4; ++j)
                xv[j] = *(const float4*)&xs[(rg * 4 + j) * 68 + k4];
#pragma unroll
            for (int q = 0; q < 4; ++q)
                wv[q] = *(const float4*)&ws[(k4 + q) * 64 + cg * 4];
#pragma unroll
            for (int j = 0; j < 4; ++j) {
                const float* xf = (const float*)&xv[j];
#pragma unroll
                for (int q = 0; q < 4; ++q) {
                    const float* wf = (const float*)&wv[q];
#pragma unroll
                    for (int i = 0; i < 4; ++i)
                        acc[j][i] = fmaf(xf[q], wf[i], acc[j][i]);
                }
            }
        }
    }

    // ---- GEMM2: elu(h) @ w1 + b1 (single 64-k tile, LDS reuse) ----
    __syncthreads();
#pragma unroll
    for (int j = 0; j < 4; ++j) {
        float4 hv;
        hv.x = eluf(acc[j][0]); hv.y = eluf(acc[j][1]);
        hv.z = eluf(acc[j][2]); hv.w = eluf(acc[j][3]);
        *(float4*)&xs[(rg * 4 + j) * 68 + cg * 4] = hv;
    }
#pragma unroll
    for (int i = 0; i < 16; ++i) {
        const int r = sr + 4 * i;
        ws[r * 64 + sk] = w1[r * CC + sk];
    }
    __syncthreads();

    float acc2[4][4];
    const float4 b1v = *(const float4*)&b1[cg * 4];
#pragma unroll
    for (int j = 0; j < 4; ++j) {
        acc2[j][0] = b1v.x; acc2[j][1] = b1v.y;
        acc2[j][2] = b1v.z; acc2[j][3] = b1v.w;
    }
#pragma unroll 4
    for (int k4 = 0; k4 < 64; k4 += 4) {
        float4 xv[4], wv[4];
#pragma unroll
        for (int j = 0; j < 4; ++j)
            xv[j] = *(const float4*)&xs[(rg * 4 + j) * 68 + k4];
#pragma unroll
        for (int q = 0; q < 4; ++q)
            wv[q] = *(const float4*)&ws[(k4 + q) * 64 + cg * 4];
#pragma unroll
        for (int j = 0; j < 4; ++j) {
            const float* xf = (const float*)&xv[j];
#pragma unroll
            for (int q = 0; q < 4; ++q) {
                const float* wf = (const float*)&wv[q];
#pragma unroll
                for (int i = 0; i < 4; ++i)
                    acc2[j][i] = fmaf(xf[q], wf[i], acc2[j][i]);
            }
        }
    }

    // ---- epilogue: write h2 to LDS, then wave-per-row hop attention ----
    __syncthreads();   // done reading ws (w1)
#pragma unroll
    for (int j = 0; j < 4; ++j)
        *(float4*)&ws[(rg * 4 + j) * 64 + cg * 4] =
            make_float4(acc2[j][0], acc2[j][1], acc2[j][2], acc2[j][3]);
    __syncthreads();

    const int c = tid & 63;
    const int wv4 = tid >> 6;
    const float ha = hop_att0[c];
    const float hb = hop_bias0[0];
#pragma unroll
    for (int rr = 0; rr < 16; ++rr) {
        const int r = wv4 + 4 * rr;
        const float v = ws[r * 64 + c];
        const float attn = wave_sum(ha * eluf(v)) + hb;
        const int row = R0 + r;
        if (row < NN) {
            xout[row * CC + c] = v;
            zout[row * CC + c] = v * attn;
        }
    }
}

// ---------------------------------------------------------------------------
// CSR build (dst-sorted): histogram -> exclusive scan -> scatter
// ---------------------------------------------------------------------------
__global__ __launch_bounds__(256) void k_hist(const int* __restrict__ ei,
                                              int* __restrict__ deg)
{
    const int e = blockIdx.x * 256 + threadIdx.x;   // grid == EE/256
    atomicAdd(&deg[ei[EE + e]], 1);
}

__global__ __launch_bounds__(256) void k_scan(const int* __restrict__ deg,
                                              int* __restrict__ offs)
{
    __shared__ int part[256];
    const int tid = threadIdx.x;
    const int start = tid * 40;
    const int end = start + 40 < NN ? start + 40 : NN;
    int sum = 0;
    for (int i = start; i < end; ++i) sum += deg[i];
    part[tid] = sum;
    __syncthreads();
    if (tid == 0) {
        int run = 0;
        for (int i = 0; i < 256; ++i) { int t = part[i]; part[i] = run; run += t; }
    }
    __syncthreads();
    int run = part[tid];
    for (int i = start; i < end; ++i) { offs[i] = run; run += deg[i]; }
}

__global__ __launch_bounds__(256) void k_scatter(
    const int* __restrict__ ei, const int* __restrict__ offs,
    int* __restrict__ cursor, int* __restrict__ csr_src,
    int* __restrict__ csr_dst)
{
    const int e = blockIdx.x * 256 + threadIdx.x;
    const int d = ei[EE + e];
    const int pos = offs[d] + atomicAdd(&cursor[d], 1);
    csr_src[pos] = ei[e];
    csr_dst[pos] = d;
}

// ---------------------------------------------------------------------------
// Group boundaries from sorted batch: gstart[g] = first node with batch>=g.
// ---------------------------------------------------------------------------
__global__ __launch_bounds__(256) void k_bounds(const int* __restrict__ batch,
                                                int* __restrict__ gstart)
{
    const int n = blockIdx.x * 256 + threadIdx.x;   // grid covers NN
    if (n >= NN) return;
    if (n == 0)
        for (int g = 0; g <= batch[0]; ++g) gstart[g] = 0;
    else {
        const int b0 = batch[n - 1], b1 = batch[n];
        for (int g = b0 + 1; g <= b1; ++g) gstart[g] = n;
    }
    if (n == NN - 1)
        for (int g = batch[NN - 1] + 1; g <= GG; ++g) gstart[g] = NN;
}

// ---------------------------------------------------------------------------
// Edge attention in CSR order: 16 lanes per edge (4 edges/wave).
// Pure compute + sequential a_csr store. NO atomics (adj via k_adj segment sum).
// ---------------------------------------------------------------------------
__global__ __launch_bounds__(256) void k_edge_att(
    const int* __restrict__ csr_src, const int* __restrict__ csr_dst,
    const float* __restrict__ z, const float* __restrict__ conv_att,
    float scale, float* __restrict__ a_csr)
{
    __shared__ float sca[CC];
    if (threadIdx.x < CC) sca[threadIdx.x] = conv_att[threadIdx.x];
    __syncthreads();

    const int e = blockIdx.x * 16 + (threadIdx.x >> 4);   // grid == EE/16
    const int l = threadIdx.x & 15;
    const int s = csr_src[e];
    const int d = csr_dst[e];
    const float4 zs = *(const float4*)(z + s * CC + l * 4);
    const float4 zd = *(const float4*)(z + d * CC + l * 4);
    float p = sca[4 * l + 0] * eluf((zs.x + zd.x) * scale);
    p = fmaf(sca[4 * l + 1], eluf((zs.y + zd.y) * scale), p);
    p = fmaf(sca[4 * l + 2], eluf((zs.z + zd.z) * scale), p);
    p = fmaf(sca[4 * l + 3], eluf((zs.w + zd.w) * scale), p);
#pragma unroll
    for (int off = 8; off > 0; off >>= 1) p += __shfl_xor(p, off, 64);
    if (l == 0)
        a_csr[e] = softplusf(p) + 1e-6f;
}

// ---------------------------------------------------------------------------
// Degree normalization: contiguous segment sum of a_csr per node (no atomics),
// store inv_adj = rsqrt(max(sum,1e-32)). One wave per node.
// ---------------------------------------------------------------------------
__global__ __launch_bounds__(256) void k_adj(
    const int* __restrict__ offs, const int* __restrict__ deg,
    const float* __restrict__ a_csr, float* __restrict__ inv_adj)
{
    const int n = blockIdx.x * 4 + (threadIdx.x >> 6);   // grid == NN/4
    const int c = threadIdx.x & 63;
    const int start = offs[n];
    const int len = deg[n];
    float s = 0.f;
    for (int i = c; i < len; i += 64) s += a_csr[start + i];
    s = wave_sum(s);
    if (c == 0) inv_adj[n] = rsqrtf(fmaxf(s, 1e-32f));
}

// ---------------------------------------------------------------------------
// Fused message gather + UpdateZ. One wave per dst node, lane = channel.
// ---------------------------------------------------------------------------
__global__ __launch_bounds__(256) void k_msg_fused(
    const int* __restrict__ offs, const int* __restrict__ deg,
    const int* __restrict__ csr_src, const float* __restrict__ a_csr,
    const float* __restrict__ inv_adj, const float* __restrict__ x,
    float* __restrict__ xn, float* __restrict__ z,
    const float* __restrict__ hop_att, const float* __restrict__ hop_bias,
    float scale)
{
    const int n = __builtin_amdgcn_readfirstlane(
        blockIdx.x * 4 + (threadIdx.x >> 6));            // grid == NN/4
    const int c = threadIdx.x & 63;
    const int start = offs[n];
    const int len = deg[n];
    const float invd = inv_adj[n];

    float acc = 0.f;
    for (int base = 0; base < len; base += 64) {
        const int cnt = (len - base) < 64 ? (len - base) : 64;
        int s_l = 0; float na_l = 0.f;
        if (c < cnt) {
            s_l = csr_src[start + base + c];
            na_l = a_csr[start + base + c] * inv_adj[s_l] * invd;
        }
        int j = 0;
        for (; j + 4 <= cnt; j += 4) {
            const int s0 = __builtin_amdgcn_readlane(s_l, j);
            const int s1 = __builtin_amdgcn_readlane(s_l, j + 1);
            const int s2 = __builtin_amdgcn_readlane(s_l, j + 2);
            const int s3 = __builtin_amdgcn_readlane(s_l, j + 3);
            const float n0 = __int_as_float(__builtin_amdgcn_readlane(__float_as_int(na_l), j));
            const float n1 = __int_as_float(__builtin_amdgcn_readlane(__float_as_int(na_l), j + 1));
            const float n2 = __int_as_float(__builtin_amdgcn_readlane(__float_as_int(na_l), j + 2));
            const float n3 = __int_as_float(__builtin_amdgcn_readlane(__float_as_int(na_l), j + 3));
            const float v0 = x[s0 * CC + c];
            const float v1 = x[s1 * CC + c];
            const float v2 = x[s2 * CC + c];
            const float v3 = x[s3 * CC + c];
            acc = fmaf(v0, n0, acc);
            acc = fmaf(v1, n1, acc);
            acc = fmaf(v2, n2, acc);
            acc = fmaf(v3, n3, acc);
        }
        for (; j < cnt; ++j) {
            const int s = __builtin_amdgcn_readlane(s_l, j);
            const float na = __int_as_float(__builtin_amdgcn_readlane(__float_as_int(na_l), j));
            acc = fmaf(x[s * CC + c], na, acc);
        }
    }

    // UpdateZ (k >= 1)
    const float zv = z[n * CC + c];
    float g = hop_att[c] * eluf(acc) + hop_att[CC + c] * eluf(zv * scale);
    const float attn = wave_sum(g) + hop_bias[0];
    z[n * CC + c] = zv + acc * attn;
    xn[n * CC + c] = acc;
}

// ---------------------------------------------------------------------------
// Fused readout: block per graph (batch is sorted -> contiguous ranges).
// ---------------------------------------------------------------------------
__global__ __launch_bounds__(256) void k_pool_head(
    const float* __restrict__ z, const int* __restrict__ gstart,
    const float* __restrict__ w_head, const float* __restrict__ b_head,
    float* __restrict__ out)
{
    __shared__ float red[4][CC];
    const int g = blockIdx.x;            // GG blocks
    const int w = threadIdx.x >> 6;
    const int c = threadIdx.x & 63;
    const int s0 = gstart[g], s1 = gstart[g + 1];

    float acc = 0.f;
    for (int n = s0 + w; n < s1; n += 4) acc += eluf(z[n * CC + c]);
    red[w][c] = acc;
    __syncthreads();
    if (w == 0) {
        const float v = red[0][c] + red[1][c] + red[2][c] + red[3][c];
        const float tot = wave_sum(v * w_head[c]);
        if (c == 0)
            out[g] = tot / fmaxf((float)(s1 - s0), 1.f) + b_head[0];
    }
}

extern "C" void kernel_launch(void* const* d_in, const int* in_sizes, int n_in,
                              void* d_out, int out_size, void* d_ws, size_t ws_size,
                              hipStream_t stream) {
    const float* x        = (const float*)d_in[0];
    const int*   ei       = (const int*)d_in[1];
    const int*   batch    = (const int*)d_in[2];
    const float* w0       = (const float*)d_in[3];
    const float* b0       = (const float*)d_in[4];
    const float* w1       = (const float*)d_in[5];
    const float* b1       = (const float*)d_in[6];
    const float* conv_att = (const float*)d_in[7];
    const float* hop_att0 = (const float*)d_in[8];
    const float* hop_bias0= (const float*)d_in[9];
    const float* hop_att  = (const float*)d_in[10];
    const float* hop_bias = (const float*)d_in[11];
    const float* w_head   = (const float*)d_in[12];
    const float* b_head   = (const float*)d_in[13];
    float* out = (float*)d_out;

    // ---- workspace layout ----
    float* xA      = (float*)d_ws;               // NN*CC
    float* xB      = xA + NN * CC;               // NN*CC
    float* zbuf    = xB + NN * CC;               // NN*CC
    float* a_csr   = zbuf + NN * CC;             // EE
    float* inv_adj = a_csr + EE;                 // NN (no zeroing needed)
    // zero block starts here:
    int*   deg     = (int*)(inv_adj + NN);       // NN
    int*   cursor  = deg + NN;                   // NN
    // end zero block
    int*   offs    = cursor + NN;                // NN
    int*   csr_src = offs + NN;                  // EE
    int*   csr_dst = csr_src + EE;               // EE
    int*   gstart  = csr_dst + EE;               // GG+1

    hipMemsetAsync(deg, 0, (size_t)(2 * NN) * 4, stream);

    k_init<<<(NN + 63) / 64, 256, 0, stream>>>(x, w0, b0, w1, b1,
                                               hop_att0, hop_bias0, xA, zbuf);
    k_hist<<<EE / 256, 256, 0, stream>>>(ei, deg);
    k_scan<<<1, 256, 0, stream>>>(deg, offs);
    k_scatter<<<EE / 256, 256, 0, stream>>>(ei, offs, cursor, csr_src, csr_dst);
    k_bounds<<<(NN + 255) / 256, 256, 0, stream>>>(batch, gstart);

    float* xcur = xA;
    float* xnext = xB;
    for (int i = 0; i < NLAYER; ++i) {
        const int k = i + 1;
        const float scale = (float)log(1.0 / (double)k + 1.0 + 1e-6);
        k_edge_att<<<EE / 16, 256, 0, stream>>>(csr_src, csr_dst, zbuf,
                                                conv_att + i * CC, scale,
                                                a_csr);
        k_adj<<<NN / 4, 256, 0, stream>>>(offs, deg, a_csr, inv_adj);
        k_msg_fused<<<NN / 4, 256, 0, stream>>>(offs, deg, csr_src, a_csr,
                                                inv_adj, xcur, xnext, zbuf,
                                                hop_att + i * 2 * CC,
                                                hop_bias + i, scale);
        float* t = xcur; xcur = xnext; xnext = t;
    }

    k_pool_head<<<GG, 256, 0, stream>>>(zbuf, gstart, w_head, b_head, out);
}

// Round 7
// 541.144 us; speedup vs baseline: 1.7511x; 1.0134x over previous
//
#include <hip/hip_runtime.h>
#include <hip/hip_bf16.h>
#include <math.h>

#define NN     10000
#define EE     320000
#define IN_CH  739
#define CC     64
#define GG     64
#define NLAYER 9

// fast elu / softplus: |abs err| ~1e-7 vs libm, threshold is 4.5e-4
__device__ __forceinline__ float eluf(float x) {
    return x > 0.f ? x : __expf(x) - 1.f;
}
__device__ __forceinline__ float softplusf(float x) {
    return fmaxf(x, 0.f) + __logf(1.f + __expf(-fabsf(x)));
}
__device__ __forceinline__ float wave_sum(float v) {
#pragma unroll
    for (int off = 32; off > 0; off >>= 1) v += __shfl_xor(v, off, 64);
    return v;
}

// ---------------------------------------------------------------------------
// GEMM1 stage 1, K-split x4: block (tile,split) computes partial
// x[64 rows] @ w0[k in 192-chunk] -> hpart[split]. 628 blocks.
// ---------------------------------------------------------------------------
__global__ __launch_bounds__(256) void k_gemm1_part(
    const float* __restrict__ x, const float* __restrict__ w0,
    float* __restrict__ hpart)
{
    __shared__ float xs[64 * 68];   // [row][k], stride 68
    __shared__ float ws[64 * 64];   // [k][col]
    const int tid = threadIdx.x;
    const int cg = tid & 15;
    const int rg = tid >> 4;
    const int split = blockIdx.x & 3;
    const int R0 = (blockIdx.x >> 2) * 64;   // 157 tiles
    const int K0 = split * 192;

    const int sk = tid & 63;
    const int sr = tid >> 6;

    float xr[16], wr[16];
    float acc[4][4] = {};

    // prefetch k-tile 0 of this split
#pragma unroll
    for (int i = 0; i < 16; ++i) {
        const int r = sr + 4 * i;
        const int gr = R0 + r;
        const int gk = K0 + sk;
        xr[i] = (gr < NN && gk < IN_CH) ? x[(size_t)gr * IN_CH + gk] : 0.f;
        const int wk = K0 + r;
        wr[i] = (wk < IN_CH) ? w0[wk * CC + sk] : 0.f;
    }

    for (int t = 0; t < 3; ++t) {
        __syncthreads();
#pragma unroll
        for (int i = 0; i < 16; ++i) {
            const int r = sr + 4 * i;
            xs[r * 68 + sk] = xr[i];
            ws[r * 64 + sk] = wr[i];
        }
        __syncthreads();
        if (t + 1 < 3) {
            const int k0 = K0 + (t + 1) * 64;
#pragma unroll
            for (int i = 0; i < 16; ++i) {
                const int r = sr + 4 * i;
                const int gr = R0 + r;
                const int gk = k0 + sk;
                xr[i] = (gr < NN && gk < IN_CH) ? x[(size_t)gr * IN_CH + gk] : 0.f;
                const int wk = k0 + r;
                wr[i] = (wk < IN_CH) ? w0[wk * CC + sk] : 0.f;
            }
        }
#pragma unroll 4
        for (int k4 = 0; k4 < 64; k4 += 4) {
            float4 xv[4], wv[4];
#pragma unroll
            for (int j = 0; j < 4; ++j)
                xv[j] = *(const float4*)&xs[(rg * 4 + j) * 68 + k4];
#pragma unroll
            for (int q = 0; q < 4; ++q)
                wv[q] = *(const float4*)&ws[(k4 + q) * 64 + cg * 4];
#pragma unroll
            for (int j = 0; j < 4; ++j) {
                const float* xf = (const float*)&xv[j];
#pragma unroll
                for (int q = 0; q < 4; ++q) {
                    const float* wf = (const float*)&wv[q];
#pragma unroll
                    for (int i = 0; i < 4; ++i)
                        acc[j][i] = fmaf(xf[q], wf[i], acc[j][i]);
                }
            }
        }
    }

#pragma unroll
    for (int j = 0; j < 4; ++j) {
        const int row = R0 + rg * 4 + j;
        if (row < NN)
            *(float4*)&hpart[((size_t)split * NN + row) * CC + cg * 4] =
                make_float4(acc[j][0], acc[j][1], acc[j][2], acc[j][3]);
    }
}

// ---------------------------------------------------------------------------
// Init stage 2: sum 4 partials + b0, elu -> GEMM2 @ w1 + b1 -> hop-attn z0.
// 313 blocks of 32 rows. Also writes zs = z * scale(k=1).
// ---------------------------------------------------------------------------
__global__ __launch_bounds__(256) void k_init2(
    const float* __restrict__ hpart,
    const float* __restrict__ b0, const float* __restrict__ w1,
    const float* __restrict__ b1,
    const float* __restrict__ hop_att0, const float* __restrict__ hop_bias0,
    float scale1,
    float* __restrict__ xout, float* __restrict__ zout,
    float* __restrict__ zsout)
{
    __shared__ float xs[32 * 68];
    __shared__ float ws[64 * 64];
    const int tid = threadIdx.x;
    const int R0 = blockIdx.x * 32;

    // sum partials + bias + elu -> xs
#pragma unroll
    for (int j = 0; j < 2; ++j) {
        const int slot = tid + 256 * j;       // 512 float4 slots
        const int row = slot >> 4;
        const int col4 = (slot & 15) * 4;
        const int grow = R0 + row;
        float4 s = make_float4(0.f, 0.f, 0.f, 0.f);
        if (grow < NN) {
#pragma unroll
            for (int sp = 0; sp < 4; ++sp) {
                const float4 v =
                    *(const float4*)&hpart[((size_t)sp * NN + grow) * CC + col4];
                s.x += v.x; s.y += v.y; s.z += v.z; s.w += v.w;
            }
        }
        const float4 bb = *(const float4*)&b0[col4];
        s.x = eluf(s.x + bb.x); s.y = eluf(s.y + bb.y);
        s.z = eluf(s.z + bb.z); s.w = eluf(s.w + bb.w);
        *(float4*)&xs[row * 68 + col4] = s;
    }
    {
        const int sk = tid & 63;
        const int sr = tid >> 6;
#pragma unroll
        for (int i = 0; i < 16; ++i)
            ws[(sr + 4 * i) * 64 + sk] = w1[(sr + 4 * i) * CC + sk];
    }
    __syncthreads();

    // GEMM2: thread = 2 rows x 4 cols
    const int cg = tid & 15;
    const int rg = tid >> 4;
    float acc2[2][4];
    const float4 b1v = *(const float4*)&b1[cg * 4];
#pragma unroll
    for (int j = 0; j < 2; ++j) {
        acc2[j][0] = b1v.x; acc2[j][1] = b1v.y;
        acc2[j][2] = b1v.z; acc2[j][3] = b1v.w;
    }
#pragma unroll 4
    for (int k4 = 0; k4 < 64; k4 += 4) {
        float4 xv[2], wv[4];
#pragma unroll
        for (int j = 0; j < 2; ++j)
            xv[j] = *(const float4*)&xs[(rg * 2 + j) * 68 + k4];
#pragma unroll
        for (int q = 0; q < 4; ++q)
            wv[q] = *(const float4*)&ws[(k4 + q) * 64 + cg * 4];
#pragma unroll
        for (int j = 0; j < 2; ++j) {
            const float* xf = (const float*)&xv[j];
#pragma unroll
            for (int q = 0; q < 4; ++q) {
                const float* wf = (const float*)&wv[q];
#pragma unroll
                for (int i = 0; i < 4; ++i)
                    acc2[j][i] = fmaf(xf[q], wf[i], acc2[j][i]);
            }
        }
    }

    __syncthreads();   // done with ws (w1)
#pragma unroll
    for (int j = 0; j < 2; ++j)
        *(float4*)&ws[(rg * 2 + j) * 64 + cg * 4] =
            make_float4(acc2[j][0], acc2[j][1], acc2[j][2], acc2[j][3]);
    __syncthreads();

    // epilogue: 4 waves x 8 rows
    const int c = tid & 63;
    const int w = tid >> 6;
    const float ha = hop_att0[c];
    const float hb = hop_bias0[0];
#pragma unroll
    for (int rr = 0; rr < 8; ++rr) {
        const int r = w * 8 + rr;
        const float v = ws[r * 64 + c];
        const float attn = wave_sum(ha * eluf(v)) + hb;
        const int row = R0 + r;
        if (row < NN) {
            const float zv = v * attn;
            xout[row * CC + c] = v;
            zout[row * CC + c] = zv;
            zsout[row * CC + c] = zv * scale1;
        }
    }
}

// ---------------------------------------------------------------------------
// CSR build (dst-sorted): histogram -> exclusive scan -> scatter
// ---------------------------------------------------------------------------
__global__ __launch_bounds__(256) void k_hist(const int* __restrict__ ei,
                                              int* __restrict__ deg)
{
    const int e = blockIdx.x * 256 + threadIdx.x;
    atomicAdd(&deg[ei[EE + e]], 1);
}

__global__ __launch_bounds__(256) void k_scan(const int* __restrict__ deg,
                                              int* __restrict__ offs)
{
    __shared__ int part[256];
    const int tid = threadIdx.x;
    const int start = tid * 40;
    const int end = start + 40 < NN ? start + 40 : NN;
    int sum = 0;
    for (int i = start; i < end; ++i) sum += deg[i];
    part[tid] = sum;
    __syncthreads();
    if (tid == 0) {
        int run = 0;
        for (int i = 0; i < 256; ++i) { int t = part[i]; part[i] = run; run += t; }
    }
    __syncthreads();
    int run = part[tid];
    for (int i = start; i < end; ++i) { offs[i] = run; run += deg[i]; }
}

__global__ __launch_bounds__(256) void k_scatter(
    const int* __restrict__ ei, const int* __restrict__ offs,
    int* __restrict__ cursor, int* __restrict__ csr_src,
    int* __restrict__ csr_dst)
{
    const int e = blockIdx.x * 256 + threadIdx.x;
    const int d = ei[EE + e];
    const int pos = offs[d] + atomicAdd(&cursor[d], 1);
    csr_src[pos] = ei[e];
    csr_dst[pos] = d;
}

__global__ __launch_bounds__(256) void k_bounds(const int* __restrict__ batch,
                                                int* __restrict__ gstart)
{
    const int n = blockIdx.x * 256 + threadIdx.x;
    if (n >= NN) return;
    if (n == 0)
        for (int g = 0; g <= batch[0]; ++g) gstart[g] = 0;
    else {
        const int b0 = batch[n - 1], b1 = batch[n];
        for (int g = b0 + 1; g <= b1; ++g) gstart[g] = n;
    }
    if (n == NN - 1)
        for (int g = batch[NN - 1] + 1; g <= GG; ++g) gstart[g] = NN;
}

// ---------------------------------------------------------------------------
// Edge attention in CSR order, reading pre-scaled zs: 16 lanes per edge.
// ---------------------------------------------------------------------------
__global__ __launch_bounds__(256) void k_edge_att(
    const int* __restrict__ csr_src, const int* __restrict__ csr_dst,
    const float* __restrict__ zs_buf, const float* __restrict__ conv_att,
    float* __restrict__ a_csr)
{
    __shared__ float sca[CC];
    if (threadIdx.x < CC) sca[threadIdx.x] = conv_att[threadIdx.x];
    __syncthreads();

    const int e = blockIdx.x * 16 + (threadIdx.x >> 4);
    const int l = threadIdx.x & 15;
    const int s = csr_src[e];
    const int d = csr_dst[e];
    const float4 zs = *(const float4*)(zs_buf + s * CC + l * 4);
    const float4 zd = *(const float4*)(zs_buf + d * CC + l * 4);
    float p = sca[4 * l + 0] * eluf(zs.x + zd.x);
    p = fmaf(sca[4 * l + 1], eluf(zs.y + zd.y), p);
    p = fmaf(sca[4 * l + 2], eluf(zs.z + zd.z), p);
    p = fmaf(sca[4 * l + 3], eluf(zs.w + zd.w), p);
#pragma unroll
    for (int off = 8; off > 0; off >>= 1) p += __shfl_xor(p, off, 64);
    if (l == 0)
        a_csr[e] = softplusf(p) + 1e-6f;
}

// ---------------------------------------------------------------------------
// Degree normalization: contiguous segment sum, no atomics. Wave per node.
// ---------------------------------------------------------------------------
__global__ __launch_bounds__(256) void k_adj(
    const int* __restrict__ offs, const int* __restrict__ deg,
    const float* __restrict__ a_csr, float* __restrict__ inv_adj)
{
    const int n = blockIdx.x * 4 + (threadIdx.x >> 6);
    const int c = threadIdx.x & 63;
    const int start = offs[n];
    const int len = deg[n];
    float s = 0.f;
    for (int i = c; i < len; i += 64) s += a_csr[start + i];
    s = wave_sum(s);
    if (c == 0) inv_adj[n] = rsqrtf(fmaxf(s, 1e-32f));
}

// ---------------------------------------------------------------------------
// Fused message gather + UpdateZ. Wave per dst node, lane = channel.
// Reads zs (current scaled z) for hop-attn; writes z and zs for next layer.
// ---------------------------------------------------------------------------
__global__ __launch_bounds__(256) void k_msg_fused(
    const int* __restrict__ offs, const int* __restrict__ deg,
    const int* __restrict__ csr_src, const float* __restrict__ a_csr,
    const float* __restrict__ inv_adj, const float* __restrict__ x,
    float* __restrict__ xn, float* __restrict__ z,
    float* __restrict__ zs_buf,
    const float* __restrict__ hop_att, const float* __restrict__ hop_bias,
    float scale_next)
{
    const int n = __builtin_amdgcn_readfirstlane(
        blockIdx.x * 4 + (threadIdx.x >> 6));
    const int c = threadIdx.x & 63;
    const int start = offs[n];
    const int len = deg[n];
    const float invd = inv_adj[n];

    float acc = 0.f;
    for (int base = 0; base < len; base += 64) {
        const int cnt = (len - base) < 64 ? (len - base) : 64;
        int s_l = 0; float na_l = 0.f;
        if (c < cnt) {
            s_l = csr_src[start + base + c];
            na_l = a_csr[start + base + c] * inv_adj[s_l] * invd;
        }
        int j = 0;
        for (; j + 4 <= cnt; j += 4) {
            const int s0 = __builtin_amdgcn_readlane(s_l, j);
            const int s1 = __builtin_amdgcn_readlane(s_l, j + 1);
            const int s2 = __builtin_amdgcn_readlane(s_l, j + 2);
            const int s3 = __builtin_amdgcn_readlane(s_l, j + 3);
            const float n0 = __int_as_float(__builtin_amdgcn_readlane(__float_as_int(na_l), j));
            const float n1 = __int_as_float(__builtin_amdgcn_readlane(__float_as_int(na_l), j + 1));
            const float n2 = __int_as_float(__builtin_amdgcn_readlane(__float_as_int(na_l), j + 2));
            const float n3 = __int_as_float(__builtin_amdgcn_readlane(__float_as_int(na_l), j + 3));
            const float v0 = x[s0 * CC + c];
            const float v1 = x[s1 * CC + c];
            const float v2 = x[s2 * CC + c];
            const float v3 = x[s3 * CC + c];
            acc = fmaf(v0, n0, acc);
            acc = fmaf(v1, n1, acc);
            acc = fmaf(v2, n2, acc);
            acc = fmaf(v3, n3, acc);
        }
        for (; j < cnt; ++j) {
            const int s = __builtin_amdgcn_readlane(s_l, j);
            const float na = __int_as_float(__builtin_amdgcn_readlane(__float_as_int(na_l), j));
            acc = fmaf(x[s * CC + c], na, acc);
        }
    }

    // UpdateZ (k >= 1): g = [h, z_scale]; z_scale is zs (already scaled)
    const float zv = z[n * CC + c];
    const float zsv = zs_buf[n * CC + c];
    float g = hop_att[c] * eluf(acc) + hop_att[CC + c] * eluf(zsv);
    const float attn = wave_sum(g) + hop_bias[0];
    const float znew = zv + acc * attn;
    z[n * CC + c] = znew;
    zs_buf[n * CC + c] = znew * scale_next;
    xn[n * CC + c] = acc;
}

// ---------------------------------------------------------------------------
// Fused readout: block per graph.
// ---------------------------------------------------------------------------
__global__ __launch_bounds__(256) void k_pool_head(
    const float* __restrict__ z, const int* __restrict__ gstart,
    const float* __restrict__ w_head, const float* __restrict__ b_head,
    float* __restrict__ out)
{
    __shared__ float red[4][CC];
    const int g = blockIdx.x;
    const int w = threadIdx.x >> 6;
    const int c = threadIdx.x & 63;
    const int s0 = gstart[g], s1 = gstart[g + 1];

    float acc = 0.f;
    for (int n = s0 + w; n < s1; n += 4) acc += eluf(z[n * CC + c]);
    red[w][c] = acc;
    __syncthreads();
    if (w == 0) {
        const float v = red[0][c] + red[1][c] + red[2][c] + red[3][c];
        const float tot = wave_sum(v * w_head[c]);
        if (c == 0)
            out[g] = tot / fmaxf((float)(s1 - s0), 1.f) + b_head[0];
    }
}

extern "C" void kernel_launch(void* const* d_in, const int* in_sizes, int n_in,
                              void* d_out, int out_size, void* d_ws, size_t ws_size,
                              hipStream_t stream) {
    const float* x        = (const float*)d_in[0];
    const int*   ei       = (const int*)d_in[1];
    const int*   batch    = (const int*)d_in[2];
    const float* w0       = (const float*)d_in[3];
    const float* b0       = (const float*)d_in[4];
    const float* w1       = (const float*)d_in[5];
    const float* b1       = (const float*)d_in[6];
    const float* conv_att = (const float*)d_in[7];
    const float* hop_att0 = (const float*)d_in[8];
    const float* hop_bias0= (const float*)d_in[9];
    const float* hop_att  = (const float*)d_in[10];
    const float* hop_bias = (const float*)d_in[11];
    const float* w_head   = (const float*)d_in[12];
    const float* b_head   = (const float*)d_in[13];
    float* out = (float*)d_out;

    // scales for k = 1..9 (host precompute)
    float sc[NLAYER + 1];
    for (int k = 1; k <= NLAYER; ++k)
        sc[k] = (float)log(1.0 / (double)k + 1.0 + 1e-6);

    // ---- workspace layout ----
    float* xA      = (float*)d_ws;               // NN*CC
    float* xB      = xA + NN * CC;               // NN*CC
    float* zbuf    = xB + NN * CC;               // NN*CC
    float* zsbuf   = zbuf + NN * CC;             // NN*CC
    float* inv_adj = zsbuf + NN * CC;            // NN
    float* hpart   = inv_adj + NN;               // 4*NN*CC — dead after k_init2
    // CSR arrays aliased INTO hpart's space (used only after k_init2):
    float* a_csr   = hpart;                      // EE
    int*   csr_src = (int*)(a_csr + EE);         // EE
    int*   csr_dst = csr_src + EE;               // EE
    int*   deg     = csr_dst + EE;               // NN  (zeroed)
    int*   cursor  = deg + NN;                   // NN  (zeroed)
    int*   offs    = cursor + NN;                // NN
    int*   gstart  = offs + NN;                  // GG+1

    k_gemm1_part<<<157 * 4, 256, 0, stream>>>(x, w0, hpart);
    k_init2<<<313, 256, 0, stream>>>(hpart, b0, w1, b1, hop_att0, hop_bias0,
                                     sc[1], xA, zbuf, zsbuf);

    hipMemsetAsync(deg, 0, (size_t)(2 * NN) * 4, stream);
    k_hist<<<EE / 256, 256, 0, stream>>>(ei, deg);
    k_scan<<<1, 256, 0, stream>>>(deg, offs);
    k_scatter<<<EE / 256, 256, 0, stream>>>(ei, offs, cursor, csr_src, csr_dst);
    k_bounds<<<(NN + 255) / 256, 256, 0, stream>>>(batch, gstart);

    float* xcur = xA;
    float* xnext = xB;
    for (int i = 0; i < NLAYER; ++i) {
        const float scale_next = (i + 1 < NLAYER) ? sc[i + 2] : 0.f;
        k_edge_att<<<EE / 16, 256, 0, stream>>>(csr_src, csr_dst, zsbuf,
                                                conv_att + i * CC, a_csr);
        k_adj<<<NN / 4, 256, 0, stream>>>(offs, deg, a_csr, inv_adj);
        k_msg_fused<<<NN / 4, 256, 0, stream>>>(offs, deg, csr_src, a_csr,
                                                inv_adj, xcur, xnext, zbuf,
                                                zsbuf,
                                                hop_att + i * 2 * CC,
                                                hop_bias + i, scale_next);
        float* t = xcur; xcur = xnext; xnext = t;
    }

    k_pool_head<<<GG, 256, 0, stream>>>(zbuf, gstart, w_head, b_head, out);
}

// Round 8
// 473.586 us; speedup vs baseline: 2.0009x; 1.1427x over previous
//
#include <hip/hip_runtime.h>
#include <hip/hip_bf16.h>
#include <math.h>

#define NN     10000
#define EE     320000
#define IN_CH  739
#define CC     64
#define GG     64
#define NLAYER 9

// fast elu / softplus: |abs err| ~1e-7 vs libm, threshold is 4.5e-4
__device__ __forceinline__ float eluf(float x) {
    return x > 0.f ? x : __expf(x) - 1.f;
}
__device__ __forceinline__ float softplusf(float x) {
    return fmaxf(x, 0.f) + __logf(1.f + __expf(-fabsf(x)));
}
__device__ __forceinline__ float wave_sum(float v) {
#pragma unroll
    for (int off = 32; off > 0; off >>= 1) v += __shfl_xor(v, off, 64);
    return v;
}

// ---------------------------------------------------------------------------
// GEMM1 stage 1, K-split x4: block (tile,split) computes partial
// x[64 rows] @ w0[k in 192-chunk] -> hpart[split]. 628 blocks.
// ---------------------------------------------------------------------------
__global__ __launch_bounds__(256) void k_gemm1_part(
    const float* __restrict__ x, const float* __restrict__ w0,
    float* __restrict__ hpart)
{
    __shared__ float xs[64 * 68];   // [row][k], stride 68
    __shared__ float ws[64 * 64];   // [k][col]
    const int tid = threadIdx.x;
    const int cg = tid & 15;
    const int rg = tid >> 4;
    const int split = blockIdx.x & 3;
    const int R0 = (blockIdx.x >> 2) * 64;   // 157 tiles
    const int K0 = split * 192;

    const int sk = tid & 63;
    const int sr = tid >> 6;

    float xr[16], wr[16];
    float acc[4][4] = {};

    // prefetch k-tile 0 of this split
#pragma unroll
    for (int i = 0; i < 16; ++i) {
        const int r = sr + 4 * i;
        const int gr = R0 + r;
        const int gk = K0 + sk;
        xr[i] = (gr < NN && gk < IN_CH) ? x[(size_t)gr * IN_CH + gk] : 0.f;
        const int wk = K0 + r;
        wr[i] = (wk < IN_CH) ? w0[wk * CC + sk] : 0.f;
    }

    for (int t = 0; t < 3; ++t) {
        __syncthreads();
#pragma unroll
        for (int i = 0; i < 16; ++i) {
            const int r = sr + 4 * i;
            xs[r * 68 + sk] = xr[i];
            ws[r * 64 + sk] = wr[i];
        }
        __syncthreads();
        if (t + 1 < 3) {
            const int k0 = K0 + (t + 1) * 64;
#pragma unroll
            for (int i = 0; i < 16; ++i) {
                const int r = sr + 4 * i;
                const int gr = R0 + r;
                const int gk = k0 + sk;
                xr[i] = (gr < NN && gk < IN_CH) ? x[(size_t)gr * IN_CH + gk] : 0.f;
                const int wk = k0 + r;
                wr[i] = (wk < IN_CH) ? w0[wk * CC + sk] : 0.f;
            }
        }
#pragma unroll 4
        for (int k4 = 0; k4 < 64; k4 += 4) {
            float4 xv[4], wv[4];
#pragma unroll
            for (int j = 0; j < 4; ++j)
                xv[j] = *(const float4*)&xs[(rg * 4 + j) * 68 + k4];
#pragma unroll
            for (int q = 0; q < 4; ++q)
                wv[q] = *(const float4*)&ws[(k4 + q) * 64 + cg * 4];
#pragma unroll
            for (int j = 0; j < 4; ++j) {
                const float* xf = (const float*)&xv[j];
#pragma unroll
                for (int q = 0; q < 4; ++q) {
                    const float* wf = (const float*)&wv[q];
#pragma unroll
                    for (int i = 0; i < 4; ++i)
                        acc[j][i] = fmaf(xf[q], wf[i], acc[j][i]);
                }
            }
        }
    }

#pragma unroll
    for (int j = 0; j < 4; ++j) {
        const int row = R0 + rg * 4 + j;
        if (row < NN)
            *(float4*)&hpart[((size_t)split * NN + row) * CC + cg * 4] =
                make_float4(acc[j][0], acc[j][1], acc[j][2], acc[j][3]);
    }
}

// ---------------------------------------------------------------------------
// Init stage 2: sum 4 partials + b0, elu -> GEMM2 @ w1 + b1 -> hop-attn z0.
// 313 blocks of 32 rows. Also writes zs = z * scale(k=1).
// ---------------------------------------------------------------------------
__global__ __launch_bounds__(256) void k_init2(
    const float* __restrict__ hpart,
    const float* __restrict__ b0, const float* __restrict__ w1,
    const float* __restrict__ b1,
    const float* __restrict__ hop_att0, const float* __restrict__ hop_bias0,
    float scale1,
    float* __restrict__ xout, float* __restrict__ zout,
    float* __restrict__ zsout)
{
    __shared__ float xs[32 * 68];
    __shared__ float ws[64 * 64];
    const int tid = threadIdx.x;
    const int R0 = blockIdx.x * 32;

    // sum partials + bias + elu -> xs
#pragma unroll
    for (int j = 0; j < 2; ++j) {
        const int slot = tid + 256 * j;       // 512 float4 slots
        const int row = slot >> 4;
        const int col4 = (slot & 15) * 4;
        const int grow = R0 + row;
        float4 s = make_float4(0.f, 0.f, 0.f, 0.f);
        if (grow < NN) {
#pragma unroll
            for (int sp = 0; sp < 4; ++sp) {
                const float4 v =
                    *(const float4*)&hpart[((size_t)sp * NN + grow) * CC + col4];
                s.x += v.x; s.y += v.y; s.z += v.z; s.w += v.w;
            }
        }
        const float4 bb = *(const float4*)&b0[col4];
        s.x = eluf(s.x + bb.x); s.y = eluf(s.y + bb.y);
        s.z = eluf(s.z + bb.z); s.w = eluf(s.w + bb.w);
        *(float4*)&xs[row * 68 + col4] = s;
    }
    {
        const int sk = tid & 63;
        const int sr = tid >> 6;
#pragma unroll
        for (int i = 0; i < 16; ++i)
            ws[(sr + 4 * i) * 64 + sk] = w1[(sr + 4 * i) * CC + sk];
    }
    __syncthreads();

    // GEMM2: thread = 2 rows x 4 cols
    const int cg = tid & 15;
    const int rg = tid >> 4;
    float acc2[2][4];
    const float4 b1v = *(const float4*)&b1[cg * 4];
#pragma unroll
    for (int j = 0; j < 2; ++j) {
        acc2[j][0] = b1v.x; acc2[j][1] = b1v.y;
        acc2[j][2] = b1v.z; acc2[j][3] = b1v.w;
    }
#pragma unroll 4
    for (int k4 = 0; k4 < 64; k4 += 4) {
        float4 xv[2], wv[4];
#pragma unroll
        for (int j = 0; j < 2; ++j)
            xv[j] = *(const float4*)&xs[(rg * 2 + j) * 68 + k4];
#pragma unroll
        for (int q = 0; q < 4; ++q)
            wv[q] = *(const float4*)&ws[(k4 + q) * 64 + cg * 4];
#pragma unroll
        for (int j = 0; j < 2; ++j) {
            const float* xf = (const float*)&xv[j];
#pragma unroll
            for (int q = 0; q < 4; ++q) {
                const float* wf = (const float*)&wv[q];
#pragma unroll
                for (int i = 0; i < 4; ++i)
                    acc2[j][i] = fmaf(xf[q], wf[i], acc2[j][i]);
            }
        }
    }

    __syncthreads();   // done with ws (w1)
#pragma unroll
    for (int j = 0; j < 2; ++j)
        *(float4*)&ws[(rg * 2 + j) * 64 + cg * 4] =
            make_float4(acc2[j][0], acc2[j][1], acc2[j][2], acc2[j][3]);
    __syncthreads();

    // epilogue: 4 waves x 8 rows
    const int c = tid & 63;
    const int w = tid >> 6;
    const float ha = hop_att0[c];
    const float hb = hop_bias0[0];
#pragma unroll
    for (int rr = 0; rr < 8; ++rr) {
        const int r = w * 8 + rr;
        const float v = ws[r * 64 + c];
        const float attn = wave_sum(ha * eluf(v)) + hb;
        const int row = R0 + r;
        if (row < NN) {
            const float zv = v * attn;
            xout[row * CC + c] = v;
            zout[row * CC + c] = zv;
            zsout[row * CC + c] = zv * scale1;
        }
    }
}

// ---------------------------------------------------------------------------
// CSR build (dst-sorted): histogram -> exclusive scan -> scatter (src only)
// ---------------------------------------------------------------------------
__global__ __launch_bounds__(256) void k_hist(const int* __restrict__ ei,
                                              int* __restrict__ deg)
{
    const int e = blockIdx.x * 256 + threadIdx.x;
    atomicAdd(&deg[ei[EE + e]], 1);
}

__global__ __launch_bounds__(256) void k_scan(const int* __restrict__ deg,
                                              int* __restrict__ offs)
{
    __shared__ int part[256];
    const int tid = threadIdx.x;
    const int start = tid * 40;
    const int end = start + 40 < NN ? start + 40 : NN;
    int sum = 0;
    for (int i = start; i < end; ++i) sum += deg[i];
    part[tid] = sum;
    __syncthreads();
    if (tid == 0) {
        int run = 0;
        for (int i = 0; i < 256; ++i) { int t = part[i]; part[i] = run; run += t; }
    }
    __syncthreads();
    int run = part[tid];
    for (int i = start; i < end; ++i) { offs[i] = run; run += deg[i]; }
}

__global__ __launch_bounds__(256) void k_scatter(
    const int* __restrict__ ei, const int* __restrict__ offs,
    int* __restrict__ cursor, int* __restrict__ csr_src)
{
    const int e = blockIdx.x * 256 + threadIdx.x;
    const int d = ei[EE + e];
    const int pos = offs[d] + atomicAdd(&cursor[d], 1);
    csr_src[pos] = ei[e];
}

__global__ __launch_bounds__(256) void k_bounds(const int* __restrict__ batch,
                                                int* __restrict__ gstart)
{
    const int n = blockIdx.x * 256 + threadIdx.x;
    if (n >= NN) return;
    if (n == 0)
        for (int g = 0; g <= batch[0]; ++g) gstart[g] = 0;
    else {
        const int b0 = batch[n - 1], b1 = batch[n];
        for (int g = b0 + 1; g <= b1; ++g) gstart[g] = n;
    }
    if (n == NN - 1)
        for (int g = batch[NN - 1] + 1; g <= GG; ++g) gstart[g] = NN;
}

// ---------------------------------------------------------------------------
// Fused edge attention + degree norm. One WAVE per dst node:
//   dst z-row loaded once; 4 edges in parallel (16 lanes each, lane=4 chans);
//   2 edges per group in flight for latency overlap; per-node a_e sum folds
//   into inv_adj with zero atomics. Writes a_csr in contiguous CSR order.
// ---------------------------------------------------------------------------
__global__ __launch_bounds__(256) void k_edge_adj(
    const int* __restrict__ offs, const int* __restrict__ deg,
    const int* __restrict__ csr_src,
    const float* __restrict__ zs_buf, const float* __restrict__ conv_att,
    float* __restrict__ a_csr, float* __restrict__ inv_adj)
{
    const int n = blockIdx.x * 4 + (threadIdx.x >> 6);   // grid == NN/4
    const int lane = threadIdx.x & 63;
    const int l = lane & 15;      // position in 16-lane group (4 channels)
    const int grp = lane >> 4;    // edge group 0..3
    const int start = offs[n];
    const int len = deg[n];

    const float4 zd = *(const float4*)(zs_buf + n * CC + l * 4);
    const float4 scv = *(const float4*)(conv_att + l * 4);

    float asum = 0.f;
    int i = grp;
    for (; i + 4 < len; i += 8) {       // 2 edges per group in flight
        const int s0 = csr_src[start + i];
        const int s1 = csr_src[start + i + 4];
        const float4 a0 = *(const float4*)(zs_buf + s0 * CC + l * 4);
        const float4 a1 = *(const float4*)(zs_buf + s1 * CC + l * 4);
        float p0 = scv.x * eluf(a0.x + zd.x);
        p0 = fmaf(scv.y, eluf(a0.y + zd.y), p0);
        p0 = fmaf(scv.z, eluf(a0.z + zd.z), p0);
        p0 = fmaf(scv.w, eluf(a0.w + zd.w), p0);
        float p1 = scv.x * eluf(a1.x + zd.x);
        p1 = fmaf(scv.y, eluf(a1.y + zd.y), p1);
        p1 = fmaf(scv.z, eluf(a1.z + zd.z), p1);
        p1 = fmaf(scv.w, eluf(a1.w + zd.w), p1);
#pragma unroll
        for (int off = 8; off > 0; off >>= 1) {
            p0 += __shfl_xor(p0, off, 64);
            p1 += __shfl_xor(p1, off, 64);
        }
        const float ae0 = softplusf(p0) + 1e-6f;
        const float ae1 = softplusf(p1) + 1e-6f;
        asum += ae0 + ae1;
        if (l == 0) {
            a_csr[start + i] = ae0;
            a_csr[start + i + 4] = ae1;
        }
    }
    for (; i < len; i += 4) {
        const int s0 = csr_src[start + i];
        const float4 a0 = *(const float4*)(zs_buf + s0 * CC + l * 4);
        float p0 = scv.x * eluf(a0.x + zd.x);
        p0 = fmaf(scv.y, eluf(a0.y + zd.y), p0);
        p0 = fmaf(scv.z, eluf(a0.z + zd.z), p0);
        p0 = fmaf(scv.w, eluf(a0.w + zd.w), p0);
#pragma unroll
        for (int off = 8; off > 0; off >>= 1) p0 += __shfl_xor(p0, off, 64);
        const float ae0 = softplusf(p0) + 1e-6f;
        asum += ae0;
        if (l == 0) a_csr[start + i] = ae0;
    }

    // cross-group reduce (asum identical within each 16-lane group)
    asum += __shfl_xor(asum, 16, 64);
    asum += __shfl_xor(asum, 32, 64);
    if (lane == 0) inv_adj[n] = rsqrtf(fmaxf(asum, 1e-32f));
}

// ---------------------------------------------------------------------------
// Fused message gather + UpdateZ. Wave per dst node, lane = channel.
// ---------------------------------------------------------------------------
__global__ __launch_bounds__(256) void k_msg_fused(
    const int* __restrict__ offs, const int* __restrict__ deg,
    const int* __restrict__ csr_src, const float* __restrict__ a_csr,
    const float* __restrict__ inv_adj, const float* __restrict__ x,
    float* __restrict__ xn, float* __restrict__ z,
    float* __restrict__ zs_buf,
    const float* __restrict__ hop_att, const float* __restrict__ hop_bias,
    float scale_next)
{
    const int n = blockIdx.x * 4 + (threadIdx.x >> 6);
    const int c = threadIdx.x & 63;
    const int start = offs[n];
    const int len = deg[n];
    const float invd = inv_adj[n];

    float acc = 0.f;
    for (int base = 0; base < len; base += 64) {
        const int cnt = (len - base) < 64 ? (len - base) : 64;
        int s_l = 0; float na_l = 0.f;
        if (c < cnt) {
            s_l = csr_src[start + base + c];
            na_l = a_csr[start + base + c] * inv_adj[s_l] * invd;
        }
        int j = 0;
        for (; j + 4 <= cnt; j += 4) {
            const int s0 = __builtin_amdgcn_readlane(s_l, j);
            const int s1 = __builtin_amdgcn_readlane(s_l, j + 1);
            const int s2 = __builtin_amdgcn_readlane(s_l, j + 2);
            const int s3 = __builtin_amdgcn_readlane(s_l, j + 3);
            const float n0 = __int_as_float(__builtin_amdgcn_readlane(__float_as_int(na_l), j));
            const float n1 = __int_as_float(__builtin_amdgcn_readlane(__float_as_int(na_l), j + 1));
            const float n2 = __int_as_float(__builtin_amdgcn_readlane(__float_as_int(na_l), j + 2));
            const float n3 = __int_as_float(__builtin_amdgcn_readlane(__float_as_int(na_l), j + 3));
            const float v0 = x[s0 * CC + c];
            const float v1 = x[s1 * CC + c];
            const float v2 = x[s2 * CC + c];
            const float v3 = x[s3 * CC + c];
            acc = fmaf(v0, n0, acc);
            acc = fmaf(v1, n1, acc);
            acc = fmaf(v2, n2, acc);
            acc = fmaf(v3, n3, acc);
        }
        for (; j < cnt; ++j) {
            const int s = __builtin_amdgcn_readlane(s_l, j);
            const float na = __int_as_float(__builtin_amdgcn_readlane(__float_as_int(na_l), j));
            acc = fmaf(x[s * CC + c], na, acc);
        }
    }

    // UpdateZ (k >= 1): g = [h, z_scale]; z_scale is zs (already scaled)
    const float zv = z[n * CC + c];
    const float zsv = zs_buf[n * CC + c];
    float g = hop_att[c] * eluf(acc) + hop_att[CC + c] * eluf(zsv);
    const float attn = wave_sum(g) + hop_bias[0];
    const float znew = zv + acc * attn;
    z[n * CC + c] = znew;
    zs_buf[n * CC + c] = znew * scale_next;
    xn[n * CC + c] = acc;
}

// ---------------------------------------------------------------------------
// Fused readout: block per graph.
// ---------------------------------------------------------------------------
__global__ __launch_bounds__(256) void k_pool_head(
    const float* __restrict__ z, const int* __restrict__ gstart,
    const float* __restrict__ w_head, const float* __restrict__ b_head,
    float* __restrict__ out)
{
    __shared__ float red[4][CC];
    const int g = blockIdx.x;
    const int w = threadIdx.x >> 6;
    const int c = threadIdx.x & 63;
    const int s0 = gstart[g], s1 = gstart[g + 1];

    float acc = 0.f;
    for (int n = s0 + w; n < s1; n += 4) acc += eluf(z[n * CC + c]);
    red[w][c] = acc;
    __syncthreads();
    if (w == 0) {
        const float v = red[0][c] + red[1][c] + red[2][c] + red[3][c];
        const float tot = wave_sum(v * w_head[c]);
        if (c == 0)
            out[g] = tot / fmaxf((float)(s1 - s0), 1.f) + b_head[0];
    }
}

extern "C" void kernel_launch(void* const* d_in, const int* in_sizes, int n_in,
                              void* d_out, int out_size, void* d_ws, size_t ws_size,
                              hipStream_t stream) {
    const float* x        = (const float*)d_in[0];
    const int*   ei       = (const int*)d_in[1];
    const int*   batch    = (const int*)d_in[2];
    const float* w0       = (const float*)d_in[3];
    const float* b0       = (const float*)d_in[4];
    const float* w1       = (const float*)d_in[5];
    const float* b1       = (const float*)d_in[6];
    const float* conv_att = (const float*)d_in[7];
    const float* hop_att0 = (const float*)d_in[8];
    const float* hop_bias0= (const float*)d_in[9];
    const float* hop_att  = (const float*)d_in[10];
    const float* hop_bias = (const float*)d_in[11];
    const float* w_head   = (const float*)d_in[12];
    const float* b_head   = (const float*)d_in[13];
    float* out = (float*)d_out;

    // scales for k = 1..9 (host precompute)
    float sc[NLAYER + 1];
    for (int k = 1; k <= NLAYER; ++k)
        sc[k] = (float)log(1.0 / (double)k + 1.0 + 1e-6);

    // ---- workspace layout ----
    float* xA      = (float*)d_ws;               // NN*CC
    float* xB      = xA + NN * CC;               // NN*CC
    float* zbuf    = xB + NN * CC;               // NN*CC
    float* zsbuf   = zbuf + NN * CC;             // NN*CC
    float* inv_adj = zsbuf + NN * CC;            // NN
    float* hpart   = inv_adj + NN;               // 4*NN*CC — dead after k_init2
    // CSR arrays aliased INTO hpart's space (used only after k_init2):
    float* a_csr   = hpart;                      // EE
    int*   csr_src = (int*)(a_csr + EE);         // EE
    int*   deg     = csr_src + EE;               // NN  (zeroed)
    int*   cursor  = deg + NN;                   // NN  (zeroed)
    int*   offs    = cursor + NN;                // NN
    int*   gstart  = offs + NN;                  // GG+1

    k_gemm1_part<<<157 * 4, 256, 0, stream>>>(x, w0, hpart);
    k_init2<<<313, 256, 0, stream>>>(hpart, b0, w1, b1, hop_att0, hop_bias0,
                                     sc[1], xA, zbuf, zsbuf);

    hipMemsetAsync(deg, 0, (size_t)(2 * NN) * 4, stream);
    k_hist<<<EE / 256, 256, 0, stream>>>(ei, deg);
    k_scan<<<1, 256, 0, stream>>>(deg, offs);
    k_scatter<<<EE / 256, 256, 0, stream>>>(ei, offs, cursor, csr_src);
    k_bounds<<<(NN + 255) / 256, 256, 0, stream>>>(batch, gstart);

    float* xcur = xA;
    float* xnext = xB;
    for (int i = 0; i < NLAYER; ++i) {
        const float scale_next = (i + 1 < NLAYER) ? sc[i + 2] : 0.f;
        k_edge_adj<<<NN / 4, 256, 0, stream>>>(offs, deg, csr_src, zsbuf,
                                               conv_att + i * CC,
                                               a_csr, inv_adj);
        k_msg_fused<<<NN / 4, 256, 0, stream>>>(offs, deg, csr_src, a_csr,
                                                inv_adj, xcur, xnext, zbuf,
                                                zsbuf,
                                                hop_att + i * 2 * CC,
                                                hop_bias + i, scale_next);
        float* t = xcur; xcur = xnext; xnext = t;
    }

    k_pool_head<<<GG, 256, 0, stream>>>(zbuf, gstart, w_head, b_head, out);
}

// Round 9
// 445.073 us; speedup vs baseline: 2.1291x; 1.0641x over previous
//
#include <hip/hip_runtime.h>
#include <hip/hip_bf16.h>
#include <math.h>

#define NN     10000
#define EE     320000
#define IN_CH  739
#define CC     64
#define GG     64
#define NLAYER 9
#define NBUCK  157    // ceil(NN/64)
#define CHUNK  2048   // edges per k_part1 block

// fast elu / softplus: |abs err| ~1e-7 vs libm, threshold is 4.5e-4
__device__ __forceinline__ float eluf(float x) {
    return x > 0.f ? x : __expf(x) - 1.f;
}
__device__ __forceinline__ float softplusf(float x) {
    return fmaxf(x, 0.f) + __logf(1.f + __expf(-fabsf(x)));
}
__device__ __forceinline__ float wave_sum(float v) {
#pragma unroll
    for (int off = 32; off > 0; off >>= 1) v += __shfl_xor(v, off, 64);
    return v;
}

// ---------------------------------------------------------------------------
// GEMM1 stage 1, K-split x4: block (tile,split) computes partial
// x[64 rows] @ w0[k in 192-chunk] -> hpart[split]. 628 blocks.
// ---------------------------------------------------------------------------
__global__ __launch_bounds__(256) void k_gemm1_part(
    const float* __restrict__ x, const float* __restrict__ w0,
    float* __restrict__ hpart)
{
    __shared__ float xs[64 * 68];   // [row][k], stride 68
    __shared__ float ws[64 * 64];   // [k][col]
    const int tid = threadIdx.x;
    const int cg = tid & 15;
    const int rg = tid >> 4;
    const int split = blockIdx.x & 3;
    const int R0 = (blockIdx.x >> 2) * 64;   // 157 tiles
    const int K0 = split * 192;

    const int sk = tid & 63;
    const int sr = tid >> 6;

    float xr[16], wr[16];
    float acc[4][4] = {};

#pragma unroll
    for (int i = 0; i < 16; ++i) {
        const int r = sr + 4 * i;
        const int gr = R0 + r;
        const int gk = K0 + sk;
        xr[i] = (gr < NN && gk < IN_CH) ? x[(size_t)gr * IN_CH + gk] : 0.f;
        const int wk = K0 + r;
        wr[i] = (wk < IN_CH) ? w0[wk * CC + sk] : 0.f;
    }

    for (int t = 0; t < 3; ++t) {
        __syncthreads();
#pragma unroll
        for (int i = 0; i < 16; ++i) {
            const int r = sr + 4 * i;
            xs[r * 68 + sk] = xr[i];
            ws[r * 64 + sk] = wr[i];
        }
        __syncthreads();
        if (t + 1 < 3) {
            const int k0 = K0 + (t + 1) * 64;
#pragma unroll
            for (int i = 0; i < 16; ++i) {
                const int r = sr + 4 * i;
                const int gr = R0 + r;
                const int gk = k0 + sk;
                xr[i] = (gr < NN && gk < IN_CH) ? x[(size_t)gr * IN_CH + gk] : 0.f;
                const int wk = k0 + r;
                wr[i] = (wk < IN_CH) ? w0[wk * CC + sk] : 0.f;
            }
        }
#pragma unroll 4
        for (int k4 = 0; k4 < 64; k4 += 4) {
            float4 xv[4], wv[4];
#pragma unroll
            for (int j = 0; j < 4; ++j)
                xv[j] = *(const float4*)&xs[(rg * 4 + j) * 68 + k4];
#pragma unroll
            for (int q = 0; q < 4; ++q)
                wv[q] = *(const float4*)&ws[(k4 + q) * 64 + cg * 4];
#pragma unroll
            for (int j = 0; j < 4; ++j) {
                const float* xf = (const float*)&xv[j];
#pragma unroll
                for (int q = 0; q < 4; ++q) {
                    const float* wf = (const float*)&wv[q];
#pragma unroll
                    for (int i = 0; i < 4; ++i)
                        acc[j][i] = fmaf(xf[q], wf[i], acc[j][i]);
                }
            }
        }
    }

#pragma unroll
    for (int j = 0; j < 4; ++j) {
        const int row = R0 + rg * 4 + j;
        if (row < NN)
            *(float4*)&hpart[((size_t)split * NN + row) * CC + cg * 4] =
                make_float4(acc[j][0], acc[j][1], acc[j][2], acc[j][3]);
    }
}

// ---------------------------------------------------------------------------
// Init stage 2: sum 4 partials + b0, elu -> GEMM2 @ w1 + b1 -> hop-attn z0.
// 313 blocks of 32 rows. Also writes zs = z * scale(k=1).
// ---------------------------------------------------------------------------
__global__ __launch_bounds__(256) void k_init2(
    const float* __restrict__ hpart,
    const float* __restrict__ b0, const float* __restrict__ w1,
    const float* __restrict__ b1,
    const float* __restrict__ hop_att0, const float* __restrict__ hop_bias0,
    float scale1,
    float* __restrict__ xout, float* __restrict__ zout,
    float* __restrict__ zsout)
{
    __shared__ float xs[32 * 68];
    __shared__ float ws[64 * 64];
    const int tid = threadIdx.x;
    const int R0 = blockIdx.x * 32;

#pragma unroll
    for (int j = 0; j < 2; ++j) {
        const int slot = tid + 256 * j;       // 512 float4 slots
        const int row = slot >> 4;
        const int col4 = (slot & 15) * 4;
        const int grow = R0 + row;
        float4 s = make_float4(0.f, 0.f, 0.f, 0.f);
        if (grow < NN) {
#pragma unroll
            for (int sp = 0; sp < 4; ++sp) {
                const float4 v =
                    *(const float4*)&hpart[((size_t)sp * NN + grow) * CC + col4];
                s.x += v.x; s.y += v.y; s.z += v.z; s.w += v.w;
            }
        }
        const float4 bb = *(const float4*)&b0[col4];
        s.x = eluf(s.x + bb.x); s.y = eluf(s.y + bb.y);
        s.z = eluf(s.z + bb.z); s.w = eluf(s.w + bb.w);
        *(float4*)&xs[row * 68 + col4] = s;
    }
    {
        const int sk = tid & 63;
        const int sr = tid >> 6;
#pragma unroll
        for (int i = 0; i < 16; ++i)
            ws[(sr + 4 * i) * 64 + sk] = w1[(sr + 4 * i) * CC + sk];
    }
    __syncthreads();

    const int cg = tid & 15;
    const int rg = tid >> 4;
    float acc2[2][4];
    const float4 b1v = *(const float4*)&b1[cg * 4];
#pragma unroll
    for (int j = 0; j < 2; ++j) {
        acc2[j][0] = b1v.x; acc2[j][1] = b1v.y;
        acc2[j][2] = b1v.z; acc2[j][3] = b1v.w;
    }
#pragma unroll 4
    for (int k4 = 0; k4 < 64; k4 += 4) {
        float4 xv[2], wv[4];
#pragma unroll
        for (int j = 0; j < 2; ++j)
            xv[j] = *(const float4*)&xs[(rg * 2 + j) * 68 + k4];
#pragma unroll
        for (int q = 0; q < 4; ++q)
            wv[q] = *(const float4*)&ws[(k4 + q) * 64 + cg * 4];
#pragma unroll
        for (int j = 0; j < 2; ++j) {
            const float* xf = (const float*)&xv[j];
#pragma unroll
            for (int q = 0; q < 4; ++q) {
                const float* wf = (const float*)&wv[q];
#pragma unroll
                for (int i = 0; i < 4; ++i)
                    acc2[j][i] = fmaf(xf[q], wf[i], acc2[j][i]);
            }
        }
    }

    __syncthreads();
#pragma unroll
    for (int j = 0; j < 2; ++j)
        *(float4*)&ws[(rg * 2 + j) * 64 + cg * 4] =
            make_float4(acc2[j][0], acc2[j][1], acc2[j][2], acc2[j][3]);
    __syncthreads();

    const int c = tid & 63;
    const int w = tid >> 6;
    const float ha = hop_att0[c];
    const float hb = hop_bias0[0];
#pragma unroll
    for (int rr = 0; rr < 8; ++rr) {
        const int r = w * 8 + rr;
        const float v = ws[r * 64 + c];
        const float attn = wave_sum(ha * eluf(v)) + hb;
        const int row = R0 + r;
        if (row < NN) {
            const float zv = v * attn;
            xout[row * CC + c] = v;
            zout[row * CC + c] = zv;
            zsout[row * CC + c] = zv * scale1;
        }
    }
}

// ---------------------------------------------------------------------------
// CSR build: histogram -> scan (also bucket bases) -> 2-pass bucket partition
// ---------------------------------------------------------------------------
__global__ __launch_bounds__(256) void k_hist(const int* __restrict__ ei,
                                              int* __restrict__ deg)
{
    const int e = blockIdx.x * 256 + threadIdx.x;
    atomicAdd(&deg[ei[EE + e]], 1);
}

__global__ __launch_bounds__(256) void k_scan(const int* __restrict__ deg,
                                              int* __restrict__ offs,
                                              int* __restrict__ bcur)
{
    __shared__ int part[256];
    const int tid = threadIdx.x;
    const int start = tid * 40;
    const int end = start + 40 < NN ? start + 40 : NN;
    int sum = 0;
    for (int i = start; i < end; ++i) sum += deg[i];
    part[tid] = sum;
    __syncthreads();
    if (tid == 0) {
        int run = 0;
        for (int i = 0; i < 256; ++i) { int t = part[i]; part[i] = run; run += t; }
    }
    __syncthreads();
    int run = part[tid];
    for (int i = start; i < end; ++i) {
        offs[i] = run;
        if ((i & 63) == 0) bcur[i >> 6] = run;   // bucket base (exclusive prefix)
        run += deg[i];
    }
}

// pass 1: partition edges into 157 coarse buckets (dst>>6), pairs (src,dst).
// Per-block LDS histogram + one global reservation per (block,bucket);
// staged reorder in LDS so global writes are sequential runs per bucket.
__global__ __launch_bounds__(256) void k_part1(
    const int* __restrict__ ei, int* __restrict__ bcur,
    int2* __restrict__ csr_pair)
{
    __shared__ int hist[NBUCK];
    __shared__ int scan_s[NBUCK];
    __shared__ int base_g[NBUCK];
    __shared__ int lcur[NBUCK];
    __shared__ int2 staged[CHUNK];
    const int tid = threadIdx.x;
    const int e0 = blockIdx.x * CHUNK;

    for (int b = tid; b < NBUCK; b += 256) { hist[b] = 0; lcur[b] = 0; }
    __syncthreads();

    int src[8], dst[8];
#pragma unroll
    for (int j = 0; j < 8; ++j) {
        const int e = e0 + tid + 256 * j;
        if (e < EE) {
            src[j] = ei[e];
            dst[j] = ei[EE + e];
            atomicAdd(&hist[dst[j] >> 6], 1);
        } else dst[j] = -1;
    }
    __syncthreads();
    if (tid == 0) {
        int run = 0;
        for (int b = 0; b < NBUCK; ++b) { scan_s[b] = run; run += hist[b]; }
    }
    __syncthreads();
    if (tid < NBUCK && hist[tid] > 0)
        base_g[tid] = atomicAdd(&bcur[tid], hist[tid]);
    __syncthreads();
#pragma unroll
    for (int j = 0; j < 8; ++j) {
        if (dst[j] >= 0) {
            const int b = dst[j] >> 6;
            const int r = atomicAdd(&lcur[b], 1);
            staged[scan_s[b] + r] = make_int2(src[j], dst[j]);
        }
    }
    __syncthreads();
    const int tot = (EE - e0) < CHUNK ? (EE - e0) : CHUNK;
    for (int i = tid; i < tot; i += 256) {
        const int2 p = staged[i];
        const int b = p.y >> 6;
        csr_pair[base_g[b] + (i - scan_s[b])] = p;
    }
}

// pass 2: within each bucket (contiguous pair range), place each edge at its
// exact CSR slot via LDS per-dst cursors. Writes stay in an ~8KB window.
__global__ __launch_bounds__(256) void k_part2(
    const int* __restrict__ offs, const int2* __restrict__ csr_pair,
    int* __restrict__ csr_src)
{
    __shared__ int lcnt[64];
    __shared__ int loffs[64];
    const int b = blockIdx.x;           // NBUCK blocks
    const int tid = threadIdx.x;
    const int d0 = b * 64;
    if (tid < 64) {
        lcnt[tid] = 0;
        const int d = d0 + tid;
        loffs[tid] = (d < NN) ? offs[d] : EE;
    }
    __syncthreads();
    const int r0 = offs[d0];
    const int r1 = (d0 + 64 < NN) ? offs[d0 + 64] : EE;
    for (int i = r0 + tid; i < r1; i += 256) {
        const int2 p = csr_pair[i];
        const int ld = p.y & 63;
        const int r = atomicAdd(&lcnt[ld], 1);
        csr_src[loffs[ld] + r] = p.x;
    }
}

__global__ __launch_bounds__(256) void k_bounds(const int* __restrict__ batch,
                                                int* __restrict__ gstart)
{
    const int n = blockIdx.x * 256 + threadIdx.x;
    if (n >= NN) return;
    if (n == 0)
        for (int g = 0; g <= batch[0]; ++g) gstart[g] = 0;
    else {
        const int b0 = batch[n - 1], b1 = batch[n];
        for (int g = b0 + 1; g <= b1; ++g) gstart[g] = n;
    }
    if (n == NN - 1)
        for (int g = batch[NN - 1] + 1; g <= GG; ++g) gstart[g] = NN;
}

// ---------------------------------------------------------------------------
// Fused edge attention + degree norm. One WAVE per dst node:
//   4 edge groups x 16 lanes, 4 edges in flight per group.
// ---------------------------------------------------------------------------
__global__ __launch_bounds__(256) void k_edge_adj(
    const int* __restrict__ offs, const int* __restrict__ deg,
    const int* __restrict__ csr_src,
    const float* __restrict__ zs_buf, const float* __restrict__ conv_att,
    float* __restrict__ a_csr, float* __restrict__ inv_adj)
{
    const int n = blockIdx.x * 4 + (threadIdx.x >> 6);   // grid == NN/4
    const int lane = threadIdx.x & 63;
    const int l = lane & 15;
    const int grp = lane >> 4;
    const int start = offs[n];
    const int len = deg[n];

    const float4 zd = *(const float4*)(zs_buf + n * CC + l * 4);
    const float4 scv = *(const float4*)(conv_att + l * 4);

    float asum = 0.f;
    int i = grp;
    for (; i + 12 < len; i += 16) {      // 4 edges in flight per group
        const int s0 = csr_src[start + i];
        const int s1 = csr_src[start + i + 4];
        const int s2 = csr_src[start + i + 8];
        const int s3 = csr_src[start + i + 12];
        const float4 a0 = *(const float4*)(zs_buf + s0 * CC + l * 4);
        const float4 a1 = *(const float4*)(zs_buf + s1 * CC + l * 4);
        const float4 a2 = *(const float4*)(zs_buf + s2 * CC + l * 4);
        const float4 a3 = *(const float4*)(zs_buf + s3 * CC + l * 4);
        float p0 = scv.x * eluf(a0.x + zd.x);
        p0 = fmaf(scv.y, eluf(a0.y + zd.y), p0);
        p0 = fmaf(scv.z, eluf(a0.z + zd.z), p0);
        p0 = fmaf(scv.w, eluf(a0.w + zd.w), p0);
        float p1 = scv.x * eluf(a1.x + zd.x);
        p1 = fmaf(scv.y, eluf(a1.y + zd.y), p1);
        p1 = fmaf(scv.z, eluf(a1.z + zd.z), p1);
        p1 = fmaf(scv.w, eluf(a1.w + zd.w), p1);
        float p2 = scv.x * eluf(a2.x + zd.x);
        p2 = fmaf(scv.y, eluf(a2.y + zd.y), p2);
        p2 = fmaf(scv.z, eluf(a2.z + zd.z), p2);
        p2 = fmaf(scv.w, eluf(a2.w + zd.w), p2);
        float p3 = scv.x * eluf(a3.x + zd.x);
        p3 = fmaf(scv.y, eluf(a3.y + zd.y), p3);
        p3 = fmaf(scv.z, eluf(a3.z + zd.z), p3);
        p3 = fmaf(scv.w, eluf(a3.w + zd.w), p3);
#pragma unroll
        for (int off = 8; off > 0; off >>= 1) {
            p0 += __shfl_xor(p0, off, 64);
            p1 += __shfl_xor(p1, off, 64);
            p2 += __shfl_xor(p2, off, 64);
            p3 += __shfl_xor(p3, off, 64);
        }
        const float ae0 = softplusf(p0) + 1e-6f;
        const float ae1 = softplusf(p1) + 1e-6f;
        const float ae2 = softplusf(p2) + 1e-6f;
        const float ae3 = softplusf(p3) + 1e-6f;
        asum += ae0 + ae1 + ae2 + ae3;
        if (l == 0) {
            a_csr[start + i] = ae0;
            a_csr[start + i + 4] = ae1;
            a_csr[start + i + 8] = ae2;
            a_csr[start + i + 12] = ae3;
        }
    }
    for (; i < len; i += 4) {
        const int s0 = csr_src[start + i];
        const float4 a0 = *(const float4*)(zs_buf + s0 * CC + l * 4);
        float p0 = scv.x * eluf(a0.x + zd.x);
        p0 = fmaf(scv.y, eluf(a0.y + zd.y), p0);
        p0 = fmaf(scv.z, eluf(a0.z + zd.z), p0);
        p0 = fmaf(scv.w, eluf(a0.w + zd.w), p0);
#pragma unroll
        for (int off = 8; off > 0; off >>= 1) p0 += __shfl_xor(p0, off, 64);
        const float ae0 = softplusf(p0) + 1e-6f;
        asum += ae0;
        if (l == 0) a_csr[start + i] = ae0;
    }

    asum += __shfl_xor(asum, 16, 64);
    asum += __shfl_xor(asum, 32, 64);
    if (lane == 0) inv_adj[n] = rsqrtf(fmaxf(asum, 1e-32f));
}

// ---------------------------------------------------------------------------
// Fused message gather + UpdateZ. Wave per dst node, lane = channel.
// 8 row-gathers in flight.
// ---------------------------------------------------------------------------
__global__ __launch_bounds__(256) void k_msg_fused(
    const int* __restrict__ offs, const int* __restrict__ deg,
    const int* __restrict__ csr_src, const float* __restrict__ a_csr,
    const float* __restrict__ inv_adj, const float* __restrict__ x,
    float* __restrict__ xn, float* __restrict__ z,
    float* __restrict__ zs_buf,
    const float* __restrict__ hop_att, const float* __restrict__ hop_bias,
    float scale_next)
{
    const int n = blockIdx.x * 4 + (threadIdx.x >> 6);
    const int c = threadIdx.x & 63;
    const int start = offs[n];
    const int len = deg[n];
    const float invd = inv_adj[n];

    float acc = 0.f;
    for (int base = 0; base < len; base += 64) {
        const int cnt = (len - base) < 64 ? (len - base) : 64;
        int s_l = 0; float na_l = 0.f;
        if (c < cnt) {
            s_l = csr_src[start + base + c];
            na_l = a_csr[start + base + c] * inv_adj[s_l] * invd;
        }
        int j = 0;
        for (; j + 8 <= cnt; j += 8) {
            int ss[8]; float nn_[8];
#pragma unroll
            for (int q = 0; q < 8; ++q) {
                ss[q] = __builtin_amdgcn_readlane(s_l, j + q);
                nn_[q] = __int_as_float(
                    __builtin_amdgcn_readlane(__float_as_int(na_l), j + q));
            }
            float vv[8];
#pragma unroll
            for (int q = 0; q < 8; ++q) vv[q] = x[ss[q] * CC + c];
#pragma unroll
            for (int q = 0; q < 8; ++q) acc = fmaf(vv[q], nn_[q], acc);
        }
        for (; j < cnt; ++j) {
            const int s = __builtin_amdgcn_readlane(s_l, j);
            const float na = __int_as_float(
                __builtin_amdgcn_readlane(__float_as_int(na_l), j));
            acc = fmaf(x[s * CC + c], na, acc);
        }
    }

    // UpdateZ (k >= 1): g = [h, z_scale]; z_scale is zs (already scaled)
    const float zv = z[n * CC + c];
    const float zsv = zs_buf[n * CC + c];
    float g = hop_att[c] * eluf(acc) + hop_att[CC + c] * eluf(zsv);
    const float attn = wave_sum(g) + hop_bias[0];
    const float znew = zv + acc * attn;
    z[n * CC + c] = znew;
    zs_buf[n * CC + c] = znew * scale_next;
    xn[n * CC + c] = acc;
}

// ---------------------------------------------------------------------------
// Fused readout: block per graph.
// ---------------------------------------------------------------------------
__global__ __launch_bounds__(256) void k_pool_head(
    const float* __restrict__ z, const int* __restrict__ gstart,
    const float* __restrict__ w_head, const float* __restrict__ b_head,
    float* __restrict__ out)
{
    __shared__ float red[4][CC];
    const int g = blockIdx.x;
    const int w = threadIdx.x >> 6;
    const int c = threadIdx.x & 63;
    const int s0 = gstart[g], s1 = gstart[g + 1];

    float acc = 0.f;
    for (int n = s0 + w; n < s1; n += 4) acc += eluf(z[n * CC + c]);
    red[w][c] = acc;
    __syncthreads();
    if (w == 0) {
        const float v = red[0][c] + red[1][c] + red[2][c] + red[3][c];
        const float tot = wave_sum(v * w_head[c]);
        if (c == 0)
            out[g] = tot / fmaxf((float)(s1 - s0), 1.f) + b_head[0];
    }
}

extern "C" void kernel_launch(void* const* d_in, const int* in_sizes, int n_in,
                              void* d_out, int out_size, void* d_ws, size_t ws_size,
                              hipStream_t stream) {
    const float* x        = (const float*)d_in[0];
    const int*   ei       = (const int*)d_in[1];
    const int*   batch    = (const int*)d_in[2];
    const float* w0       = (const float*)d_in[3];
    const float* b0       = (const float*)d_in[4];
    const float* w1       = (const float*)d_in[5];
    const float* b1       = (const float*)d_in[6];
    const float* conv_att = (const float*)d_in[7];
    const float* hop_att0 = (const float*)d_in[8];
    const float* hop_bias0= (const float*)d_in[9];
    const float* hop_att  = (const float*)d_in[10];
    const float* hop_bias = (const float*)d_in[11];
    const float* w_head   = (const float*)d_in[12];
    const float* b_head   = (const float*)d_in[13];
    float* out = (float*)d_out;

    float sc[NLAYER + 1];
    for (int k = 1; k <= NLAYER; ++k)
        sc[k] = (float)log(1.0 / (double)k + 1.0 + 1e-6);

    // ---- workspace layout ----
    float* xA      = (float*)d_ws;               // NN*CC
    float* xB      = xA + NN * CC;               // NN*CC
    float* zbuf    = xB + NN * CC;               // NN*CC
    float* zsbuf   = zbuf + NN * CC;             // NN*CC
    float* inv_adj = zsbuf + NN * CC;            // NN
    float* hpart   = inv_adj + NN;               // 4*NN*CC — dead after k_init2
    // CSR arrays aliased INTO hpart's space (used only after k_init2):
    float* a_csr   = hpart;                      // EE
    int*   csr_src = (int*)(a_csr + EE);         // EE
    int2*  csr_pair= (int2*)(csr_src + EE);      // EE pairs (2*EE ints)
    int*   deg     = (int*)(csr_pair + EE);      // NN  (zeroed)
    int*   offs    = deg + NN;                   // NN
    int*   bcur    = offs + NN;                  // NBUCK
    int*   gstart  = bcur + NBUCK;               // GG+1

    k_gemm1_part<<<157 * 4, 256, 0, stream>>>(x, w0, hpart);
    k_init2<<<313, 256, 0, stream>>>(hpart, b0, w1, b1, hop_att0, hop_bias0,
                                     sc[1], xA, zbuf, zsbuf);

    hipMemsetAsync(deg, 0, (size_t)NN * 4, stream);
    k_hist<<<EE / 256, 256, 0, stream>>>(ei, deg);
    k_scan<<<1, 256, 0, stream>>>(deg, offs, bcur);
    k_part1<<<(EE + CHUNK - 1) / CHUNK, 256, 0, stream>>>(ei, bcur, csr_pair);
    k_part2<<<NBUCK, 256, 0, stream>>>(offs, csr_pair, csr_src);
    k_bounds<<<(NN + 255) / 256, 256, 0, stream>>>(batch, gstart);

    float* xcur = xA;
    float* xnext = xB;
    for (int i = 0; i < NLAYER; ++i) {
        const float scale_next = (i + 1 < NLAYER) ? sc[i + 2] : 0.f;
        k_edge_adj<<<NN / 4, 256, 0, stream>>>(offs, deg, csr_src, zsbuf,
                                               conv_att + i * CC,
                                               a_csr, inv_adj);
        k_msg_fused<<<NN / 4, 256, 0, stream>>>(offs, deg, csr_src, a_csr,
                                                inv_adj, xcur, xnext, zbuf,
                                                zsbuf,
                                                hop_att + i * 2 * CC,
                                                hop_bias + i, scale_next);
        float* t = xcur; xcur = xnext; xnext = t;
    }

    k_pool_head<<<GG, 256, 0, stream>>>(zbuf, gstart, w_head, b_head, out);
}